// Round 1
// baseline (271.888 us; speedup 1.0000x reference)
//
#include <hip/hip_runtime.h>
#include <hip/hip_bf16.h>

typedef __bf16 bf16_t;
typedef __attribute__((ext_vector_type(8))) __bf16 bf16x8;
typedef __attribute__((ext_vector_type(4))) __bf16 bf16x4;
typedef __attribute__((ext_vector_type(4))) float f32x4;

#define B_ 2
#define T_ 2048
#define D_ 1024
#define H_ 16
#define DH_ 64

static __device__ __forceinline__ f32x4 mfma16(bf16x8 a, bf16x8 b, f32x4 c) {
  return __builtin_amdgcn_mfma_f32_16x16x32_bf16(a, b, c, 0, 0, 0);
}

// ---------------- fp32 -> bf16 conversion (vectorized) ----------------
__global__ __launch_bounds__(256) void cvt_f32_bf16(const float* __restrict__ in,
                                                    bf16_t* __restrict__ out, int n4) {
  int i = blockIdx.x * 256 + threadIdx.x;
  if (i >= n4) return;
  float4 f = reinterpret_cast<const float4*>(in)[i];
  bf16x4 o;
  o[0] = (bf16_t)f.x; o[1] = (bf16_t)f.y; o[2] = (bf16_t)f.z; o[3] = (bf16_t)f.w;
  reinterpret_cast<bf16x4*>(out)[i] = o;
}

// ---------------- NT GEMM: C[M,N] = A[M,K] * B[N,K]^T  (bf16 in, fp32 acc) ----------------
// 128x128 tile, BK=64, 4 waves each computing a 64x64 quadrant as 4x4 16x16 frags.
template <bool STORE_F32>
__global__ __launch_bounds__(256) void gemm_nt(const bf16_t* __restrict__ A,
                                               const bf16_t* __restrict__ Bm,
                                               void* __restrict__ Cv,
                                               int M, int N, int K) {
  __shared__ __align__(16) bf16_t As[128][72];
  __shared__ __align__(16) bf16_t Bs[128][72];
  const int tid  = threadIdx.x;
  const int lane = tid & 63;
  const int wave = tid >> 6;
  const int brow = blockIdx.y * 128;
  const int bcol = blockIdx.x * 128;
  const int row0 = (wave >> 1) * 64;
  const int col0 = (wave & 1) * 64;

  f32x4 acc[4][4];
#pragma unroll
  for (int m = 0; m < 4; ++m)
#pragma unroll
    for (int n = 0; n < 4; ++n) acc[m][n] = f32x4{0.f, 0.f, 0.f, 0.f};

  for (int k0 = 0; k0 < K; k0 += 64) {
#pragma unroll
    for (int i = 0; i < 4; ++i) {
      int c = tid + 256 * i;
      int r = c >> 3, kc = (c & 7) * 8;
      *reinterpret_cast<bf16x8*>(&As[r][kc]) =
          *reinterpret_cast<const bf16x8*>(&A[(size_t)(brow + r) * K + k0 + kc]);
      *reinterpret_cast<bf16x8*>(&Bs[r][kc]) =
          *reinterpret_cast<const bf16x8*>(&Bm[(size_t)(bcol + r) * K + k0 + kc]);
    }
    __syncthreads();
#pragma unroll
    for (int kk = 0; kk < 2; ++kk) {
      const int ko = kk * 32 + (lane >> 4) * 8;
      bf16x8 af[4], bfr[4];
#pragma unroll
      for (int m = 0; m < 4; ++m)
        af[m] = *reinterpret_cast<const bf16x8*>(&As[row0 + 16 * m + (lane & 15)][ko]);
#pragma unroll
      for (int n = 0; n < 4; ++n)
        bfr[n] = *reinterpret_cast<const bf16x8*>(&Bs[col0 + 16 * n + (lane & 15)][ko]);
#pragma unroll
      for (int m = 0; m < 4; ++m)
#pragma unroll
        for (int n = 0; n < 4; ++n) acc[m][n] = mfma16(af[m], bfr[n], acc[m][n]);
    }
    __syncthreads();
  }

  // epilogue: C/D layout col=lane&15, row=(lane>>4)*4+reg  [verified m89/m91]
  const int crow = brow + row0 + (lane >> 4) * 4;
  const int ccol = bcol + col0 + (lane & 15);
#pragma unroll
  for (int m = 0; m < 4; ++m)
#pragma unroll
    for (int n = 0; n < 4; ++n)
#pragma unroll
      for (int r = 0; r < 4; ++r) {
        size_t idx = (size_t)(crow + 16 * m + r) * N + (ccol + 16 * n);
        if (STORE_F32)
          reinterpret_cast<float*>(Cv)[idx] = acc[m][n][r];
        else
          reinterpret_cast<bf16_t*>(Cv)[idx] = (bf16_t)acc[m][n][r];
      }
}

// ---------------- causal flash attention ----------------
// grid: (T/64, B*H), 256 threads = 4 waves, each wave owns 16 q rows.
// q/k/v/ctx all in [B,T,D] layout, head h occupies columns h*64..h*64+63.
__global__ __launch_bounds__(256) void attn_fwd(const bf16_t* __restrict__ Q,
                                                const bf16_t* __restrict__ Kp,
                                                const bf16_t* __restrict__ V,
                                                bf16_t* __restrict__ Ctx) {
  __shared__ __align__(16) bf16_t Ks[64][72];
  __shared__ __align__(16) bf16_t Vts[64][72];   // transposed V: Vts[dh][k]
  __shared__ __align__(16) bf16_t Ps[4][16][72]; // per-wave P tile
  const int tid  = threadIdx.x;
  const int lane = tid & 63;
  const int wave = tid >> 6;
  const int qt = blockIdx.x;
  const int bh = blockIdx.y;
  const int b = bh >> 4, h = bh & 15;
  const size_t base = ((size_t)b * T_) * D_ + h * DH_;
  const int qw0 = qt * 64 + wave * 16;

  // Q fragments (held in registers for the whole kernel)
  bf16x8 qf[2];
  {
    int qr = qw0 + (lane & 15);
    int d0 = (lane >> 4) * 8;
    qf[0] = *reinterpret_cast<const bf16x8*>(&Q[base + (size_t)qr * D_ + d0]);
    qf[1] = *reinterpret_cast<const bf16x8*>(&Q[base + (size_t)qr * D_ + 32 + d0]);
  }

  f32x4 o[4];
  float mrow[4], lrow[4];
#pragma unroll
  for (int j = 0; j < 4; ++j) o[j] = f32x4{0.f, 0.f, 0.f, 0.f};
#pragma unroll
  for (int r = 0; r < 4; ++r) { mrow[r] = -1e30f; lrow[r] = 0.f; }

  const int nkt = qt + 1;  // causal: only tiles up to the diagonal
  for (int kt = 0; kt < nkt; ++kt) {
    __syncthreads();  // all waves done with previous Ks/Vts
#pragma unroll
    for (int i = 0; i < 2; ++i) {
      int c = tid + 256 * i;
      int r = c >> 3, d0 = (c & 7) * 8;
      *reinterpret_cast<bf16x8*>(&Ks[r][d0]) =
          *reinterpret_cast<const bf16x8*>(&Kp[base + (size_t)(kt * 64 + r) * D_ + d0]);
      bf16x8 vv = *reinterpret_cast<const bf16x8*>(&V[base + (size_t)(kt * 64 + r) * D_ + d0]);
#pragma unroll
      for (int j = 0; j < 8; ++j) Vts[d0 + j][r] = vv[j];
    }
    __syncthreads();

    // S = Q K^T for this wave's 16 rows x 64 cols
    f32x4 s[4];
#pragma unroll
    for (int n = 0; n < 4; ++n) {
      f32x4 sa = f32x4{0.f, 0.f, 0.f, 0.f};
#pragma unroll
      for (int kk = 0; kk < 2; ++kk) {
        bf16x8 kf = *reinterpret_cast<const bf16x8*>(
            &Ks[16 * n + (lane & 15)][kk * 32 + (lane >> 4) * 8]);
        sa = mfma16(qf[kk], kf, sa);
      }
      s[n] = sa;
    }

    // scale + causal mask
    const int qrow0 = qw0 + (lane >> 4) * 4;
#pragma unroll
    for (int n = 0; n < 4; ++n) {
      int kg = kt * 64 + 16 * n + (lane & 15);
#pragma unroll
      for (int r = 0; r < 4; ++r) {
        float val = s[n][r] * 0.125f;  // 1/sqrt(64)
        if (kg > qrow0 + r) val = -1e30f;
        s[n][r] = val;
      }
    }

    // online softmax, row stats live in the 16-lane group owning the row
#pragma unroll
    for (int r = 0; r < 4; ++r) {
      float tmax = fmaxf(fmaxf(s[0][r], s[1][r]), fmaxf(s[2][r], s[3][r]));
#pragma unroll
      for (int off = 1; off < 16; off <<= 1) tmax = fmaxf(tmax, __shfl_xor(tmax, off, 64));
      float mnew = fmaxf(mrow[r], tmax);
      float sc = __expf(mrow[r] - mnew);
      float psum = 0.f;
#pragma unroll
      for (int n = 0; n < 4; ++n) {
        float p = __expf(s[n][r] - mnew);
        s[n][r] = p;
        psum += p;
      }
#pragma unroll
      for (int off = 1; off < 16; off <<= 1) psum += __shfl_xor(psum, off, 64);
      lrow[r] = lrow[r] * sc + psum;
      mrow[r] = mnew;
#pragma unroll
      for (int j = 0; j < 4; ++j) o[j][r] *= sc;
    }

    // P -> per-wave LDS (re-layout for MFMA A operand)
#pragma unroll
    for (int n = 0; n < 4; ++n)
#pragma unroll
      for (int r = 0; r < 4; ++r)
        Ps[wave][(lane >> 4) * 4 + r][16 * n + (lane & 15)] = (bf16_t)s[n][r];

    // O += P * V   (wave-local P; compiler orders same-wave LDS ops)
#pragma unroll
    for (int j = 0; j < 4; ++j)
#pragma unroll
      for (int kk = 0; kk < 2; ++kk) {
        bf16x8 pf = *reinterpret_cast<const bf16x8*>(
            &Ps[wave][lane & 15][kk * 32 + (lane >> 4) * 8]);
        bf16x8 vf = *reinterpret_cast<const bf16x8*>(
            &Vts[16 * j + (lane & 15)][kk * 32 + (lane >> 4) * 8]);
        o[j] = mfma16(pf, vf, o[j]);
      }
  }

  // epilogue: divide by row sum, store ctx in [B,T,D]
#pragma unroll
  for (int j = 0; j < 4; ++j)
#pragma unroll
    for (int r = 0; r < 4; ++r) {
      int qrow = qw0 + (lane >> 4) * 4 + r;
      float val = o[j][r] / lrow[r];
      Ctx[base + (size_t)qrow * D_ + 16 * j + (lane & 15)] = (bf16_t)val;
    }
}

// ---------------- launch ----------------
extern "C" void kernel_launch(void* const* d_in, const int* in_sizes, int n_in,
                              void* d_out, int out_size, void* d_ws, size_t ws_size,
                              hipStream_t stream) {
  const float* x   = (const float*)d_in[0];
  const float* w_q = (const float*)d_in[1];
  const float* w_k = (const float*)d_in[2];
  const float* w_v = (const float*)d_in[3];
  const float* w_o = (const float*)d_in[4];

  const int M = B_ * T_;          // 4096
  const size_t XN = (size_t)M * D_;      // 4M elems
  const size_t WN = (size_t)D_ * D_;     // 1M elems

  bf16_t* ws = (bf16_t*)d_ws;
  bf16_t* xb  = ws;                 // 4M
  bf16_t* wqb = xb + XN;            // 1M
  bf16_t* wkb = wqb + WN;
  bf16_t* wvb = wkb + WN;
  bf16_t* wob = wvb + WN;
  bf16_t* qb  = wob + WN;           // 4M each
  bf16_t* kb  = qb + XN;
  bf16_t* vb  = kb + XN;
  bf16_t* ctx = vb + XN;

  // conversions
  cvt_f32_bf16<<<(int)(XN / 4 + 255) / 256, 256, 0, stream>>>(x, xb, (int)(XN / 4));
  cvt_f32_bf16<<<(int)(WN / 4 + 255) / 256, 256, 0, stream>>>(w_q, wqb, (int)(WN / 4));
  cvt_f32_bf16<<<(int)(WN / 4 + 255) / 256, 256, 0, stream>>>(w_k, wkb, (int)(WN / 4));
  cvt_f32_bf16<<<(int)(WN / 4 + 255) / 256, 256, 0, stream>>>(w_v, wvb, (int)(WN / 4));
  cvt_f32_bf16<<<(int)(WN / 4 + 255) / 256, 256, 0, stream>>>(w_o, wob, (int)(WN / 4));

  dim3 ggrid(D_ / 128, M / 128);  // (8, 32)
  gemm_nt<false><<<ggrid, 256, 0, stream>>>(xb, wqb, qb, M, D_, D_);
  gemm_nt<false><<<ggrid, 256, 0, stream>>>(xb, wkb, kb, M, D_, D_);
  gemm_nt<false><<<ggrid, 256, 0, stream>>>(xb, wvb, vb, M, D_, D_);

  attn_fwd<<<dim3(T_ / 64, B_ * H_), 256, 0, stream>>>(qb, kb, vb, ctx);

  gemm_nt<true><<<ggrid, 256, 0, stream>>>(ctx, wob, d_out, M, D_, D_);
}

// Round 2
// 191.385 us; speedup vs baseline: 1.4206x; 1.4206x over previous
//
#include <hip/hip_runtime.h>
#include <hip/hip_bf16.h>

typedef __bf16 bf16_t;
typedef __attribute__((ext_vector_type(8))) __bf16 bf16x8;
typedef __attribute__((ext_vector_type(4))) __bf16 bf16x4;
typedef __attribute__((ext_vector_type(4))) float f32x4;

#define B_ 2
#define T_ 2048
#define D_ 1024
#define H_ 16
#define DH_ 64
#define NQT (T_ / 64)  // 32

static __device__ __forceinline__ f32x4 mfma16(bf16x8 a, bf16x8 b, f32x4 c) {
  return __builtin_amdgcn_mfma_f32_16x16x32_bf16(a, b, c, 0, 0, 0);
}

// async global->LDS, 16B per lane. LDS dest = base + lane*16 (wave-uniform base).
static __device__ __forceinline__ void gld16(const bf16_t* g, bf16_t* l) {
  __builtin_amdgcn_global_load_lds(
      (const __attribute__((address_space(1))) unsigned int*)g,
      (__attribute__((address_space(3))) unsigned int*)l, 16, 0, 0);
}

// ---------------- fp32 -> bf16 conversion ----------------
__global__ __launch_bounds__(256) void cvt_x(const float* __restrict__ in,
                                             bf16_t* __restrict__ out, int n4) {
  int i = blockIdx.x * 256 + threadIdx.x;
  if (i >= n4) return;
  float4 f = reinterpret_cast<const float4*>(in)[i];
  bf16x4 o;
  o[0] = (bf16_t)f.x; o[1] = (bf16_t)f.y; o[2] = (bf16_t)f.z; o[3] = (bf16_t)f.w;
  reinterpret_cast<bf16x4*>(out)[i] = o;
}

__global__ __launch_bounds__(256) void cvt_w4(const float* __restrict__ w0,
                                              const float* __restrict__ w1,
                                              const float* __restrict__ w2,
                                              const float* __restrict__ w3,
                                              bf16_t* __restrict__ out, int n4each) {
  const float* in = blockIdx.y == 0 ? w0 : blockIdx.y == 1 ? w1 : blockIdx.y == 2 ? w2 : w3;
  bf16_t* o = out + (size_t)blockIdx.y * (size_t)n4each * 4;
  int i = blockIdx.x * 256 + threadIdx.x;
  if (i >= n4each) return;
  float4 f = reinterpret_cast<const float4*>(in)[i];
  bf16x4 v;
  v[0] = (bf16_t)f.x; v[1] = (bf16_t)f.y; v[2] = (bf16_t)f.z; v[3] = (bf16_t)f.w;
  reinterpret_cast<bf16x4*>(o)[i] = v;
}

// ---------------- NT GEMM (m97 structure): C = A * B^T, global_load_lds staging ----------------
template <bool STORE_F32>
__global__ __launch_bounds__(256) void gemm_nt(const bf16_t* __restrict__ A,
                                               const bf16_t* __restrict__ Bm,
                                               void* __restrict__ Cv,
                                               int M, int N, int K, float cscale) {
  __shared__ __align__(16) bf16_t As[128 * 64];
  __shared__ __align__(16) bf16_t Bs[128 * 64];
  const int tid = threadIdx.x, lane = tid & 63, wave = tid >> 6;
  const int brow = blockIdx.y * 128, bcol = blockIdx.x * 128;
  const int row0 = (wave >> 1) * 64, col0 = (wave & 1) * 64;
  const int lrow = lane >> 3, lcol = (lane & 7) * 8;

  f32x4 acc[4][4];
#pragma unroll
  for (int m = 0; m < 4; ++m)
#pragma unroll
    for (int n = 0; n < 4; ++n) acc[m][n] = f32x4{0.f, 0.f, 0.f, 0.f};

  for (int k0 = 0; k0 < K; k0 += 64) {
    const bf16_t* ga = A + (size_t)(brow + 32 * wave + lrow) * K + k0 + lcol;
    const bf16_t* gb = Bm + (size_t)(bcol + 32 * wave + lrow) * K + k0 + lcol;
#pragma unroll
    for (int s = 0; s < 4; ++s) {
      gld16(ga + (size_t)(8 * s) * K, &As[(32 * wave + 8 * s) * 64]);
      gld16(gb + (size_t)(8 * s) * K, &Bs[(32 * wave + 8 * s) * 64]);
    }
    __syncthreads();
#pragma unroll
    for (int kk = 0; kk < 2; ++kk) {
      const int ko = kk * 32 + (lane >> 4) * 8;
      bf16x8 af[4], bfr[4];
#pragma unroll
      for (int m = 0; m < 4; ++m)
        af[m] = *(const bf16x8*)&As[(row0 + 16 * m + (lane & 15)) * 64 + ko];
#pragma unroll
      for (int n = 0; n < 4; ++n)
        bfr[n] = *(const bf16x8*)&Bs[(col0 + 16 * n + (lane & 15)) * 64 + ko];
#pragma unroll
      for (int m = 0; m < 4; ++m)
#pragma unroll
        for (int n = 0; n < 4; ++n) acc[m][n] = mfma16(af[m], bfr[n], acc[m][n]);
    }
    __syncthreads();
  }
  const int crow = brow + row0 + (lane >> 4) * 4;
  const int ccol = bcol + col0 + (lane & 15);
#pragma unroll
  for (int m = 0; m < 4; ++m)
#pragma unroll
    for (int n = 0; n < 4; ++n)
#pragma unroll
      for (int r = 0; r < 4; ++r) {
        size_t idx = (size_t)(crow + 16 * m + r) * N + (ccol + 16 * n);
        float v = acc[m][n][r] * cscale;
        if (STORE_F32) reinterpret_cast<float*>(Cv)[idx] = v;
        else reinterpret_cast<bf16_t*>(Cv)[idx] = (bf16_t)v;
      }
}

// ---------------- causal flash attention ----------------
// grid (NQT/2, B*H); block z handles q-tiles z and NQT-1-z (33 K-tiles total: balanced).
// Swizzled LDS layouts (conflict-free writes AND reads, derivation in journal):
static __device__ __forceinline__ int ks_idx(int r, int d) {
  return r * 64 + (d ^ ((r & 7) << 3));
}
static __device__ __forceinline__ int vt_idx(int n, int k) {
  return n * 64 + (k ^ ((((n & 7) ^ ((n >> 3) & 7))) << 3));
}

__global__ __launch_bounds__(256) void attn_fwd(const bf16_t* __restrict__ Q,
                                                const bf16_t* __restrict__ Kp,
                                                const bf16_t* __restrict__ V,
                                                bf16_t* __restrict__ Ctx) {
  __shared__ __align__(16) bf16_t Ks[2][64 * 64];
  __shared__ __align__(16) bf16_t Vs[2][64 * 64];  // transposed: Vt[dh][k], swizzled
  __shared__ __align__(16) bf16_t Ps[4][16][72];
  const int tid = threadIdx.x, lane = tid & 63, wave = tid >> 6;
  const int z = blockIdx.x, bh = blockIdx.y;
  const int b = bh >> 4, h = bh & 15;
  const size_t base = ((size_t)b * T_) * D_ + h * DH_;

#pragma unroll 1
  for (int phase = 0; phase < 2; ++phase) {
    const int qt = phase ? (NQT - 1 - z) : z;
    const int qw0 = qt * 64 + wave * 16;

    bf16x8 qf[2];
    {
      int qr = qw0 + (lane & 15);
      int dq = (lane >> 4) * 8;
      qf[0] = *(const bf16x8*)&Q[base + (size_t)qr * D_ + dq];
      qf[1] = *(const bf16x8*)&Q[base + (size_t)qr * D_ + 32 + dq];
    }

    f32x4 o[4];
    float mrow[4], lrow[4];
#pragma unroll
    for (int j = 0; j < 4; ++j) o[j] = f32x4{0.f, 0.f, 0.f, 0.f};
#pragma unroll
    for (int r = 0; r < 4; ++r) { mrow[r] = -1e30f; lrow[r] = 0.f; }

    const int nkt = qt + 1;
    bf16x8 kreg[2], vreg[2];
    // prologue: load tile 0 into regs
#pragma unroll
    for (int it = 0; it < 2; ++it) {
      int c = tid + 256 * it, r = c >> 3, d0 = (c & 7) * 8;
      kreg[it] = *(const bf16x8*)&Kp[base + (size_t)r * D_ + d0];
      vreg[it] = *(const bf16x8*)&V[base + (size_t)r * D_ + d0];
    }
    __syncthreads();  // previous phase done reading LDS
#pragma unroll
    for (int it = 0; it < 2; ++it) {
      int c = tid + 256 * it, r = c >> 3, d0 = (c & 7) * 8;
      *(bf16x8*)&Ks[0][ks_idx(r, d0)] = kreg[it];
#pragma unroll
      for (int j = 0; j < 8; ++j) Vs[0][vt_idx(d0 + j, r)] = vreg[it][j];
    }
    int buf = 0;

    for (int kt = 0; kt < nkt; ++kt) {
      __syncthreads();  // LDS[buf] ready for all waves
      if (kt + 1 < nkt) {  // async: next tile global->reg, overlaps compute
#pragma unroll
        for (int it = 0; it < 2; ++it) {
          int c = tid + 256 * it, r = c >> 3, d0 = (c & 7) * 8;
          kreg[it] = *(const bf16x8*)&Kp[base + (size_t)((kt + 1) * 64 + r) * D_ + d0];
          vreg[it] = *(const bf16x8*)&V[base + (size_t)((kt + 1) * 64 + r) * D_ + d0];
        }
      }
      // S = Q K^T (Q pre-scaled by 1/sqrt(DH) in the GEMM)
      f32x4 s[4];
#pragma unroll
      for (int n = 0; n < 4; ++n) {
        f32x4 sa = f32x4{0.f, 0.f, 0.f, 0.f};
#pragma unroll
        for (int kk = 0; kk < 2; ++kk) {
          bf16x8 kf = *(const bf16x8*)&Ks[buf][ks_idx(16 * n + (lane & 15),
                                                      kk * 32 + (lane >> 4) * 8)];
          sa = mfma16(qf[kk], kf, sa);
        }
        s[n] = sa;
      }
      if (kt == qt) {  // causal mask only on the diagonal tile
        const int qrow0 = qw0 + (lane >> 4) * 4;
#pragma unroll
        for (int n = 0; n < 4; ++n) {
          int kg = kt * 64 + 16 * n + (lane & 15);
#pragma unroll
          for (int r = 0; r < 4; ++r)
            if (kg > qrow0 + r) s[n][r] = -1e30f;
        }
      }
      // online softmax (16-lane row groups)
#pragma unroll
      for (int r = 0; r < 4; ++r) {
        float tmax = fmaxf(fmaxf(s[0][r], s[1][r]), fmaxf(s[2][r], s[3][r]));
#pragma unroll
        for (int off = 1; off < 16; off <<= 1) tmax = fmaxf(tmax, __shfl_xor(tmax, off, 64));
        float mnew = fmaxf(mrow[r], tmax);
        float sc = __expf(mrow[r] - mnew);
        float psum = 0.f;
#pragma unroll
        for (int n = 0; n < 4; ++n) {
          float p = __expf(s[n][r] - mnew);
          s[n][r] = p;
          psum += p;
        }
#pragma unroll
        for (int off = 1; off < 16; off <<= 1) psum += __shfl_xor(psum, off, 64);
        lrow[r] = lrow[r] * sc + psum;
        mrow[r] = mnew;
#pragma unroll
        for (int j2 = 0; j2 < 4; ++j2) o[j2][r] *= sc;
      }
      // P -> per-wave LDS (A-operand re-layout)
#pragma unroll
      for (int n = 0; n < 4; ++n)
#pragma unroll
        for (int r = 0; r < 4; ++r)
          Ps[wave][(lane >> 4) * 4 + r][16 * n + (lane & 15)] = (bf16_t)s[n][r];
      // O += P * V
#pragma unroll
      for (int j2 = 0; j2 < 4; ++j2)
#pragma unroll
        for (int kk = 0; kk < 2; ++kk) {
          bf16x8 pf = *(const bf16x8*)&Ps[wave][lane & 15][kk * 32 + (lane >> 4) * 8];
          bf16x8 vf = *(const bf16x8*)&Vs[buf][vt_idx(16 * j2 + (lane & 15),
                                                      kk * 32 + (lane >> 4) * 8)];
          o[j2] = mfma16(pf, vf, o[j2]);
        }
      __syncthreads();  // all waves done reading buf^1 region; safe to overwrite
      if (kt + 1 < nkt) {
        const int nb = buf ^ 1;
#pragma unroll
        for (int it = 0; it < 2; ++it) {
          int c = tid + 256 * it, r = c >> 3, d0 = (c & 7) * 8;
          *(bf16x8*)&Ks[nb][ks_idx(r, d0)] = kreg[it];
#pragma unroll
          for (int j = 0; j < 8; ++j) Vs[nb][vt_idx(d0 + j, r)] = vreg[it][j];
        }
        buf = nb;
      }
    }
    // epilogue
#pragma unroll
    for (int j2 = 0; j2 < 4; ++j2)
#pragma unroll
      for (int r = 0; r < 4; ++r) {
        int qrow = qw0 + (lane >> 4) * 4 + r;
        Ctx[base + (size_t)qrow * D_ + 16 * j2 + (lane & 15)] = (bf16_t)(o[j2][r] / lrow[r]);
      }
  }
}

// ---------------- launch ----------------
extern "C" void kernel_launch(void* const* d_in, const int* in_sizes, int n_in,
                              void* d_out, int out_size, void* d_ws, size_t ws_size,
                              hipStream_t stream) {
  const float* x   = (const float*)d_in[0];
  const float* w_q = (const float*)d_in[1];
  const float* w_k = (const float*)d_in[2];
  const float* w_v = (const float*)d_in[3];
  const float* w_o = (const float*)d_in[4];

  const int M = B_ * T_;             // 4096
  const size_t XN = (size_t)M * D_;  // 4M elems
  const size_t WN = (size_t)D_ * D_; // 1M elems

  bf16_t* ws = (bf16_t*)d_ws;
  bf16_t* xb  = ws;
  bf16_t* wqb = xb + XN;
  bf16_t* wkb = wqb + WN;
  bf16_t* wvb = wkb + WN;
  bf16_t* wob = wvb + WN;
  bf16_t* qb  = wob + WN;
  bf16_t* kb  = qb + XN;
  bf16_t* vb  = kb + XN;
  bf16_t* ctx = vb + XN;

  cvt_x<<<(int)(XN / 4 / 256), 256, 0, stream>>>(x, xb, (int)(XN / 4));
  cvt_w4<<<dim3((int)(WN / 4 / 256), 4), 256, 0, stream>>>(w_q, w_k, w_v, w_o, wqb, (int)(WN / 4));

  dim3 ggrid(D_ / 128, M / 128);  // (8, 32)
  gemm_nt<false><<<ggrid, 256, 0, stream>>>(xb, wqb, qb, M, D_, D_, 0.125f);  // Q pre-scaled
  gemm_nt<false><<<ggrid, 256, 0, stream>>>(xb, wkb, kb, M, D_, D_, 1.0f);
  gemm_nt<false><<<ggrid, 256, 0, stream>>>(xb, wvb, vb, M, D_, D_, 1.0f);

  attn_fwd<<<dim3(NQT / 2, B_ * H_), 256, 0, stream>>>(qb, kb, vb, ctx);

  gemm_nt<true><<<ggrid, 256, 0, stream>>>(ctx, wob, d_out, M, D_, D_, 1.0f);
}

// Round 3
// 184.090 us; speedup vs baseline: 1.4769x; 1.0396x over previous
//
#include <hip/hip_runtime.h>
#include <hip/hip_bf16.h>

typedef __bf16 bf16_t;
typedef __attribute__((ext_vector_type(8))) __bf16 bf16x8;
typedef __attribute__((ext_vector_type(4))) __bf16 bf16x4;
typedef __attribute__((ext_vector_type(4))) float f32x4;
typedef __attribute__((ext_vector_type(16))) float f32x16;
typedef __attribute__((ext_vector_type(2))) int i32x2;

#define B_ 2
#define T_ 2048
#define D_ 1024
#define H_ 16
#define DH_ 64
#define RS_ 3072  // fused qkv row stride

static __device__ __forceinline__ f32x4 mfma16(bf16x8 a, bf16x8 b, f32x4 c) {
  return __builtin_amdgcn_mfma_f32_16x16x32_bf16(a, b, c, 0, 0, 0);
}
static __device__ __forceinline__ f32x16 mfma32(bf16x8 a, bf16x8 b, f32x16 c) {
  return __builtin_amdgcn_mfma_f32_32x32x16_bf16(a, b, c, 0, 0, 0);
}
static __device__ __forceinline__ void gld16(const bf16_t* g, bf16_t* l) {
  __builtin_amdgcn_global_load_lds(
      (const __attribute__((address_space(1))) unsigned int*)g,
      (__attribute__((address_space(3))) unsigned int*)l, 16, 0, 0);
}
static __device__ __forceinline__ unsigned lds_addr(const bf16_t* p) {
  return (unsigned)(uintptr_t)(const __attribute__((address_space(3))) bf16_t*)p;
}
static __device__ __forceinline__ i32x2 tr64(unsigned a) {
  i32x2 d;
  asm volatile("ds_read_b64_tr_b16 %0, %1" : "=v"(d) : "v"(a));
  return d;
}
static __device__ __forceinline__ i32x2 tr64o(unsigned a) {  // +128B (4 k-rows)
  i32x2 d;
  asm volatile("ds_read_b64_tr_b16 %0, %1 offset:128" : "=v"(d) : "v"(a));
  return d;
}
static __device__ __forceinline__ unsigned pk2(float lo, float hi2) {
  unsigned short a = __builtin_bit_cast(unsigned short, (bf16_t)lo);
  unsigned short b = __builtin_bit_cast(unsigned short, (bf16_t)hi2);
  return (unsigned)a | ((unsigned)b << 16);
}

// ---------------- fp32 -> bf16 conversion ----------------
__global__ __launch_bounds__(256) void cvt_x(const float* __restrict__ in,
                                             bf16_t* __restrict__ out, int n4) {
  int i = blockIdx.x * 256 + threadIdx.x;
  if (i >= n4) return;
  float4 f = reinterpret_cast<const float4*>(in)[i];
  bf16x4 o;
  o[0] = (bf16_t)f.x; o[1] = (bf16_t)f.y; o[2] = (bf16_t)f.z; o[3] = (bf16_t)f.w;
  reinterpret_cast<bf16x4*>(out)[i] = o;
}

__global__ __launch_bounds__(256) void cvt_w4(const float* __restrict__ w0,
                                              const float* __restrict__ w1,
                                              const float* __restrict__ w2,
                                              const float* __restrict__ w3,
                                              bf16_t* __restrict__ out, int n4each) {
  const float* in = blockIdx.y == 0 ? w0 : blockIdx.y == 1 ? w1 : blockIdx.y == 2 ? w2 : w3;
  bf16_t* o = out + (size_t)blockIdx.y * (size_t)n4each * 4;
  int i = blockIdx.x * 256 + threadIdx.x;
  if (i >= n4each) return;
  float4 f = reinterpret_cast<const float4*>(in)[i];
  bf16x4 v;
  v[0] = (bf16_t)f.x; v[1] = (bf16_t)f.y; v[2] = (bf16_t)f.z; v[3] = (bf16_t)f.w;
  reinterpret_cast<bf16x4*>(o)[i] = v;
}

// ---------------- NT GEMM: C = A * B^T, global_load_lds staging (m97) ----------------
template <bool STORE_F32, bool QSCALE>
__global__ __launch_bounds__(256) void gemm_nt(const bf16_t* __restrict__ A,
                                               const bf16_t* __restrict__ Bm,
                                               void* __restrict__ Cv,
                                               int M, int N, int K) {
  __shared__ __align__(16) bf16_t As[128 * 64];
  __shared__ __align__(16) bf16_t Bs[128 * 64];
  const int tid = threadIdx.x, lane = tid & 63, wave = tid >> 6;
  const int brow = blockIdx.y * 128, bcol = blockIdx.x * 128;
  const int row0 = (wave >> 1) * 64, col0 = (wave & 1) * 64;
  const int lrow = lane >> 3, lcol = (lane & 7) * 8;
  const float cscale = (QSCALE && bcol < 1024) ? 0.125f : 1.0f;

  f32x4 acc[4][4];
#pragma unroll
  for (int m = 0; m < 4; ++m)
#pragma unroll
    for (int n = 0; n < 4; ++n) acc[m][n] = f32x4{0.f, 0.f, 0.f, 0.f};

  for (int k0 = 0; k0 < K; k0 += 64) {
    const bf16_t* ga = A + (size_t)(brow + 32 * wave + lrow) * K + k0 + lcol;
    const bf16_t* gb = Bm + (size_t)(bcol + 32 * wave + lrow) * K + k0 + lcol;
#pragma unroll
    for (int s = 0; s < 4; ++s) {
      gld16(ga + (size_t)(8 * s) * K, &As[(32 * wave + 8 * s) * 64]);
      gld16(gb + (size_t)(8 * s) * K, &Bs[(32 * wave + 8 * s) * 64]);
    }
    __syncthreads();
#pragma unroll
    for (int kk = 0; kk < 2; ++kk) {
      const int ko = kk * 32 + (lane >> 4) * 8;
      bf16x8 af[4], bfr[4];
#pragma unroll
      for (int m = 0; m < 4; ++m)
        af[m] = *(const bf16x8*)&As[(row0 + 16 * m + (lane & 15)) * 64 + ko];
#pragma unroll
      for (int n = 0; n < 4; ++n)
        bfr[n] = *(const bf16x8*)&Bs[(col0 + 16 * n + (lane & 15)) * 64 + ko];
#pragma unroll
      for (int m = 0; m < 4; ++m)
#pragma unroll
        for (int n = 0; n < 4; ++n) acc[m][n] = mfma16(af[m], bfr[n], acc[m][n]);
    }
    __syncthreads();
  }
  const int crow = brow + row0 + (lane >> 4) * 4;
  const int ccol = bcol + col0 + (lane & 15);
#pragma unroll
  for (int m = 0; m < 4; ++m)
#pragma unroll
    for (int n = 0; n < 4; ++n)
#pragma unroll
      for (int r = 0; r < 4; ++r) {
        size_t idx = (size_t)(crow + 16 * m + r) * N + (ccol + 16 * n);
        float v = acc[m][n][r] * cscale;
        if (STORE_F32) reinterpret_cast<float*>(Cv)[idx] = v;
        else reinterpret_cast<bf16_t*>(Cv)[idx] = (bf16_t)v;
      }
}

// ---------------- causal flash attention: 1 wave = 64 q rows, barrier-free ----------------
// grid (16, 32); block = 2 waves; wave w -> q-chunk (w ? 31-z : z)  => 33 tiles/block.
// LDS per wave: dbuf x (K 8KB linear-swizzled + V 8KB 16-wide panels).
#define CROW(r) ((((r) & 3) + 8 * ((r) >> 2)) + 4 * hi)

__global__ __launch_bounds__(128, 1) void attn_fwd(const bf16_t* __restrict__ qkv,
                                                   bf16_t* __restrict__ ctx) {
  __shared__ __align__(128) bf16_t lds[2][2][2][64 * 64];  // [wave][buf][K|V][4096]
  const int lane = threadIdx.x & 63;
  const int wv = threadIdx.x >> 6;
  const int z = blockIdx.x, bh = blockIdx.y;
  const int b = bh >> 4, h = bh & 15;
  const int qt = wv ? (31 - z) : z;  // 64-row q chunk
  const bf16_t* Qg = qkv + (size_t)b * T_ * RS_ + h * DH_;
  const bf16_t* Kg = Qg + 1024;
  const bf16_t* Vg = Qg + 2048;
  bf16_t* Cg = ctx + (size_t)b * T_ * D_ + h * DH_;

  const int hi = lane >> 5;
  const int l31 = lane & 31;
  const int l15 = lane & 15;

  // Q fragments (regs for whole phase): qf[subtile][dstep]
  bf16x8 qf[2][4];
#pragma unroll
  for (int s = 0; s < 2; ++s)
#pragma unroll
    for (int d = 0; d < 4; ++d)
      qf[s][d] = *(const bf16x8*)&Qg[(size_t)(qt * 64 + s * 32 + l31) * RS_ + d * 16 + hi * 8];

  f32x16 o[2][2];
#pragma unroll
  for (int s = 0; s < 2; ++s)
#pragma unroll
    for (int n = 0; n < 2; ++n)
#pragma unroll
      for (int r = 0; r < 16; ++r) o[s][n][r] = 0.f;
  float mrow[2] = {-1e30f, -1e30f}, lsum[2] = {0.f, 0.f};

  bf16_t* Kl[2] = {&lds[wv][0][0][0], &lds[wv][1][0][0]};
  bf16_t* Vl[2] = {&lds[wv][0][1][0], &lds[wv][1][1][0]};

  const int nkt = qt + 1;

  // staging: K linear rows with col-granule XOR swizzle; V 16-wide panels
  auto stage = [&](int bi, int kt) {
#pragma unroll
    for (int i = 0; i < 8; ++i) {
      int c = i * 64 + lane;
      int r = c >> 3, g8 = (c & 7) ^ (r & 7);
      gld16(Kg + (size_t)(kt * 64 + r) * RS_ + g8 * 8, Kl[bi] + i * 512);
    }
#pragma unroll
    for (int i = 0; i < 8; ++i) {
      int c = i * 64 + lane;
      int p = c >> 7, k = (c >> 1) & 63, half = c & 1;
      gld16(Vg + (size_t)(kt * 64 + k) * RS_ + p * 16 + half * 8, Vl[bi] + i * 512);
    }
  };
  stage(0, 0);
  int buf = 0;

#pragma unroll 1
  for (int kt = 0; kt < nkt; ++kt) {
    asm volatile("s_waitcnt vmcnt(0)" ::: "memory");
    __builtin_amdgcn_sched_barrier(0);
    if (kt + 1 < nkt) stage(buf ^ 1, kt + 1);

    // K fragments: kf[t][dstep], row = 32t + l31, col granule (dstep*2+hi) ^ (row&7)
    bf16x8 kf[2][4];
#pragma unroll
    for (int t = 0; t < 2; ++t)
#pragma unroll
      for (int d = 0; d < 4; ++d) {
        int row = 32 * t + l31;
        int col = ((d * 2 + hi) ^ (row & 7)) * 8;
        kf[t][d] = *(const bf16x8*)&Kl[buf][row * 64 + col];
      }
    // V fragments via transpose-read: vf[n2][ks]
    bf16x8 vf[2][4];
    {
      unsigned vb = lds_addr(Vl[buf]);
#pragma unroll
      for (int n2 = 0; n2 < 2; ++n2)
#pragma unroll
        for (int ks = 0; ks < 4; ++ks) {
          int p = 2 * n2 + (l31 >> 4);
          int k0 = ks * 16 + hi * 8;
          unsigned a = vb + p * 2048 + k0 * 32 + l15 * 8;
          i32x2 lo = tr64(a);
          i32x2 hi4 = tr64o(a);
          union { unsigned u[4]; bf16x8 v; } uu;
          uu.u[0] = (unsigned)lo[0]; uu.u[1] = (unsigned)lo[1];
          uu.u[2] = (unsigned)hi4[0]; uu.u[3] = (unsigned)hi4[1];
          vf[n2][ks] = uu.v;
        }
    }
    asm volatile("s_waitcnt lgkmcnt(0)" ::: "memory");
    __builtin_amdgcn_sched_barrier(0);

#pragma unroll
    for (int s = 0; s < 2; ++s) {
      // S^T = K Q^T : st[t] covers k rows 32t..32t+31, q col = l31
      f32x16 st[2];
#pragma unroll
      for (int t = 0; t < 2; ++t) {
#pragma unroll
        for (int r = 0; r < 16; ++r) st[t][r] = 0.f;
#pragma unroll
        for (int d = 0; d < 4; ++d) st[t] = mfma32(kf[t][d], qf[s][d], st[t]);
      }
      if (kt == qt) {  // causal mask (diagonal tile only)
#pragma unroll
        for (int t = 0; t < 2; ++t)
#pragma unroll
          for (int r = 0; r < 16; ++r)
            if (32 * t + CROW(r) > s * 32 + l31) st[t][r] = -1e30f;
      }
      // row max (lane-local 32 + partner)
      float pm = -1e30f;
#pragma unroll
      for (int t = 0; t < 2; ++t)
#pragma unroll
        for (int r = 0; r < 16; ++r) pm = fmaxf(pm, st[t][r]);
      pm = fmaxf(pm, __shfl_xor(pm, 32));
      // defer-max: rescale only when max grew past THR
      if (!__all(pm - mrow[s] <= 8.0f)) {
        float mn = fmaxf(mrow[s], pm);
        float scl = __expf(mrow[s] - mn);
        mrow[s] = mn;
        lsum[s] *= scl;
#pragma unroll
        for (int r = 0; r < 16; ++r) {
          float sr = __shfl(scl, CROW(r));
          o[s][0][r] *= sr;
          o[s][1][r] *= sr;
        }
      }
      // exp + row sum
      float ps = 0.f;
#pragma unroll
      for (int t = 0; t < 2; ++t)
#pragma unroll
        for (int r = 0; r < 16; ++r) {
          float e = __expf(st[t][r] - mrow[s]);
          st[t][r] = e;
          ps += e;
        }
      ps += __shfl_xor(ps, 32);
      lsum[s] += ps;
      // pack P pairs: pk[t][j] = (p[2j], p[2j+1])
      unsigned pk[2][8];
#pragma unroll
      for (int t = 0; t < 2; ++t)
#pragma unroll
        for (int j = 0; j < 8; ++j) pk[t][j] = pk2(st[t][2 * j], st[t][2 * j + 1]);
      // PA fragments via single cross-half exchange per ks, then PV
#pragma unroll
      for (int ks = 0; ks < 4; ++ks) {
        const int t = ks >> 1, rb = (ks & 1) * 4;
        unsigned s0 = hi ? pk[t][rb] : pk[t][rb + 2];
        unsigned s1 = hi ? pk[t][rb + 1] : pk[t][rb + 3];
        unsigned r0 = (unsigned)__shfl_xor((int)s0, 32);
        unsigned r1 = (unsigned)__shfl_xor((int)s1, 32);
        union { unsigned u[4]; bf16x8 v; } w;
        if (hi == 0) {
          w.u[0] = pk[t][rb]; w.u[1] = pk[t][rb + 1]; w.u[2] = r0; w.u[3] = r1;
        } else {
          w.u[0] = r0; w.u[1] = r1; w.u[2] = pk[t][rb + 2]; w.u[3] = pk[t][rb + 3];
        }
        o[s][0] = mfma32(w.v, vf[0][ks], o[s][0]);
        o[s][1] = mfma32(w.v, vf[1][ks], o[s][1]);
      }
    }
    buf ^= 1;
  }

  // epilogue: O / l, store ctx rows crow(r,hi)
#pragma unroll
  for (int s = 0; s < 2; ++s)
#pragma unroll
    for (int r = 0; r < 16; ++r) {
      float li = __shfl(lsum[s], CROW(r));
      float inv = 1.0f / li;
      int qrow = qt * 64 + s * 32 + CROW(r);
#pragma unroll
      for (int n2 = 0; n2 < 2; ++n2)
        Cg[(size_t)qrow * D_ + n2 * 32 + l31] = (bf16_t)(o[s][n2][r] * inv);
    }
}

// ---------------- launch ----------------
extern "C" void kernel_launch(void* const* d_in, const int* in_sizes, int n_in,
                              void* d_out, int out_size, void* d_ws, size_t ws_size,
                              hipStream_t stream) {
  const float* x   = (const float*)d_in[0];
  const float* w_q = (const float*)d_in[1];
  const float* w_k = (const float*)d_in[2];
  const float* w_v = (const float*)d_in[3];
  const float* w_o = (const float*)d_in[4];

  const int M = B_ * T_;              // 4096
  const size_t XN = (size_t)M * D_;   // 4M
  const size_t WN = (size_t)D_ * D_;  // 1M

  bf16_t* ws = (bf16_t*)d_ws;
  bf16_t* xb   = ws;            // 4M
  bf16_t* wqb  = xb + XN;       // 3M (q,k,v) + 1M (o) contiguous
  bf16_t* wob  = wqb + 3 * WN;
  bf16_t* qkv  = wob + WN;      // [4096][3072] = 12M
  bf16_t* ctx  = qkv + (size_t)M * RS_;  // 4M

  cvt_x<<<(int)(XN / 4 / 256), 256, 0, stream>>>(x, xb, (int)(XN / 4));
  cvt_w4<<<dim3((int)(WN / 4 / 256), 4), 256, 0, stream>>>(w_q, w_k, w_v, w_o, wqb, (int)(WN / 4));

  // fused QKV GEMM: B = [w_q; w_k; w_v] (3072 x 1024), q-part pre-scaled 1/8
  gemm_nt<false, true><<<dim3(RS_ / 128, M / 128), 256, 0, stream>>>(xb, wqb, qkv, M, RS_, D_);

  attn_fwd<<<dim3(16, B_ * H_), 128, 0, stream>>>(qkv, ctx);

  gemm_nt<true, false><<<dim3(D_ / 128, M / 128), 256, 0, stream>>>(ctx, wob, d_out, M, D_, D_);
}

// Round 4
// 173.386 us; speedup vs baseline: 1.5681x; 1.0617x over previous
//
#include <hip/hip_runtime.h>
#include <hip/hip_bf16.h>

typedef __bf16 bf16_t;
typedef __attribute__((ext_vector_type(8))) __bf16 bf16x8;
typedef __attribute__((ext_vector_type(4))) __bf16 bf16x4;
typedef __attribute__((ext_vector_type(4))) float f32x4;
typedef __attribute__((ext_vector_type(16))) float f32x16;
typedef __attribute__((ext_vector_type(2))) int i32x2;

#define B_ 2
#define T_ 2048
#define D_ 1024
#define H_ 16
#define DH_ 64
#define RS_ 3072  // fused qkv row stride

static __device__ __forceinline__ f32x4 mfma16(bf16x8 a, bf16x8 b, f32x4 c) {
  return __builtin_amdgcn_mfma_f32_16x16x32_bf16(a, b, c, 0, 0, 0);
}
static __device__ __forceinline__ f32x16 mfma32(bf16x8 a, bf16x8 b, f32x16 c) {
  return __builtin_amdgcn_mfma_f32_32x32x16_bf16(a, b, c, 0, 0, 0);
}
static __device__ __forceinline__ void gld16(const bf16_t* g, bf16_t* l) {
  __builtin_amdgcn_global_load_lds(
      (const __attribute__((address_space(1))) unsigned int*)g,
      (__attribute__((address_space(3))) unsigned int*)l, 16, 0, 0);
}
static __device__ __forceinline__ unsigned lds_addr(const bf16_t* p) {
  return (unsigned)(uintptr_t)(const __attribute__((address_space(3))) bf16_t*)p;
}
static __device__ __forceinline__ i32x2 tr64(unsigned a) {
  i32x2 d;
  asm volatile("ds_read_b64_tr_b16 %0, %1" : "=v"(d) : "v"(a));
  return d;
}
static __device__ __forceinline__ i32x2 tr64o(unsigned a) {  // +128B (4 k-rows)
  i32x2 d;
  asm volatile("ds_read_b64_tr_b16 %0, %1 offset:128" : "=v"(d) : "v"(a));
  return d;
}
static __device__ __forceinline__ unsigned pk2(float lo, float hi2) {
  unsigned short a = __builtin_bit_cast(unsigned short, (bf16_t)lo);
  unsigned short b = __builtin_bit_cast(unsigned short, (bf16_t)hi2);
  return (unsigned)a | ((unsigned)b << 16);
}

// ---------------- fp32 -> bf16 conversion ----------------
__global__ __launch_bounds__(256) void cvt_x(const float* __restrict__ in,
                                             bf16_t* __restrict__ out, int n4) {
  int i = blockIdx.x * 256 + threadIdx.x;
  if (i >= n4) return;
  float4 f = reinterpret_cast<const float4*>(in)[i];
  bf16x4 o;
  o[0] = (bf16_t)f.x; o[1] = (bf16_t)f.y; o[2] = (bf16_t)f.z; o[3] = (bf16_t)f.w;
  reinterpret_cast<bf16x4*>(out)[i] = o;
}

__global__ __launch_bounds__(256) void cvt_w4(const float* __restrict__ w0,
                                              const float* __restrict__ w1,
                                              const float* __restrict__ w2,
                                              const float* __restrict__ w3,
                                              bf16_t* __restrict__ out, int n4each) {
  const float* in = blockIdx.y == 0 ? w0 : blockIdx.y == 1 ? w1 : blockIdx.y == 2 ? w2 : w3;
  bf16_t* o = out + (size_t)blockIdx.y * (size_t)n4each * 4;
  int i = blockIdx.x * 256 + threadIdx.x;
  if (i >= n4each) return;
  float4 f = reinterpret_cast<const float4*>(in)[i];
  bf16x4 v;
  v[0] = (bf16_t)f.x; v[1] = (bf16_t)f.y; v[2] = (bf16_t)f.z; v[3] = (bf16_t)f.w;
  reinterpret_cast<bf16x4*>(o)[i] = v;
}

// ---------------- NT GEMM: C = A * B^T, global_load_lds staging (m97) ----------------
template <bool STORE_F32, bool QSCALE>
__global__ __launch_bounds__(256) void gemm_nt(const bf16_t* __restrict__ A,
                                               const bf16_t* __restrict__ Bm,
                                               void* __restrict__ Cv,
                                               int M, int N, int K) {
  __shared__ __align__(16) bf16_t As[128 * 64];
  __shared__ __align__(16) bf16_t Bs[128 * 64];
  const int tid = threadIdx.x, lane = tid & 63, wave = tid >> 6;
  const int brow = blockIdx.y * 128, bcol = blockIdx.x * 128;
  const int row0 = (wave >> 1) * 64, col0 = (wave & 1) * 64;
  const int lrow = lane >> 3, lcol = (lane & 7) * 8;
  // q-part pre-scaled by (1/sqrt(DH)) * log2(e) -> softmax runs in exp2 domain
  const float cscale = (QSCALE && bcol < 1024) ? 0.18033688011112042f : 1.0f;

  f32x4 acc[4][4];
#pragma unroll
  for (int m = 0; m < 4; ++m)
#pragma unroll
    for (int n = 0; n < 4; ++n) acc[m][n] = f32x4{0.f, 0.f, 0.f, 0.f};

  for (int k0 = 0; k0 < K; k0 += 64) {
    const bf16_t* ga = A + (size_t)(brow + 32 * wave + lrow) * K + k0 + lcol;
    const bf16_t* gb = Bm + (size_t)(bcol + 32 * wave + lrow) * K + k0 + lcol;
#pragma unroll
    for (int s = 0; s < 4; ++s) {
      gld16(ga + (size_t)(8 * s) * K, &As[(32 * wave + 8 * s) * 64]);
      gld16(gb + (size_t)(8 * s) * K, &Bs[(32 * wave + 8 * s) * 64]);
    }
    __syncthreads();
#pragma unroll
    for (int kk = 0; kk < 2; ++kk) {
      const int ko = kk * 32 + (lane >> 4) * 8;
      bf16x8 af[4], bfr[4];
#pragma unroll
      for (int m = 0; m < 4; ++m)
        af[m] = *(const bf16x8*)&As[(row0 + 16 * m + (lane & 15)) * 64 + ko];
#pragma unroll
      for (int n = 0; n < 4; ++n)
        bfr[n] = *(const bf16x8*)&Bs[(col0 + 16 * n + (lane & 15)) * 64 + ko];
#pragma unroll
      for (int m = 0; m < 4; ++m)
#pragma unroll
        for (int n = 0; n < 4; ++n) acc[m][n] = mfma16(af[m], bfr[n], acc[m][n]);
    }
    __syncthreads();
  }
  const int crow = brow + row0 + (lane >> 4) * 4;
  const int ccol = bcol + col0 + (lane & 15);
#pragma unroll
  for (int m = 0; m < 4; ++m)
#pragma unroll
    for (int n = 0; n < 4; ++n)
#pragma unroll
      for (int r = 0; r < 4; ++r) {
        size_t idx = (size_t)(crow + 16 * m + r) * N + (ccol + 16 * n);
        float v = acc[m][n][r] * cscale;
        if (STORE_F32) reinterpret_cast<float*>(Cv)[idx] = v;
        else reinterpret_cast<bf16_t*>(Cv)[idx] = (bf16_t)v;
      }
}

// ---------------- causal flash attention: 1 wave = 1 block = 32 q rows ----------------
// grid (64, 32): 2048 independent single-wave blocks; dynamic scheduling smooths the
// causal imbalance (longest chunks launched first). 16KB LDS, ~2 waves/SIMD by VGPR.
#define CROW(r) ((((r) & 3) + 8 * ((r) >> 2)) + 4 * hi)

__global__ __launch_bounds__(64, 2) void attn_fwd(const bf16_t* __restrict__ qkv,
                                                  bf16_t* __restrict__ ctx) {
  __shared__ __align__(128) bf16_t Ks[64 * 64];        // row-major, 8-elem XOR swizzle
  __shared__ __align__(128) bf16_t Vs[4 * 64 * 16];    // 16-wide panels for tr_b16
  const int lane = threadIdx.x;
  const int c = 63 - (int)blockIdx.x;   // q-chunk (rows 32c..32c+31), longest-first
  const int bh = blockIdx.y;
  const int b = bh >> 4, h = bh & 15;
  const bf16_t* Qg = qkv + (size_t)b * T_ * RS_ + h * DH_;
  const bf16_t* Kg = Qg + 1024;
  const bf16_t* Vg = Qg + 2048;
  bf16_t* Cg = ctx + (size_t)b * T_ * D_ + h * DH_;

  const int hi = lane >> 5;
  const int l31 = lane & 31;
  const int l15 = lane & 15;
  const int q0 = c * 32;

  // Q fragments (exp2-domain pre-scaled), kept in regs
  bf16x8 qf[4];
#pragma unroll
  for (int d = 0; d < 4; ++d)
    qf[d] = *(const bf16x8*)&Qg[(size_t)(q0 + l31) * RS_ + d * 16 + hi * 8];

  f32x16 o[2];
#pragma unroll
  for (int n = 0; n < 2; ++n)
#pragma unroll
    for (int r = 0; r < 16; ++r) o[n][r] = 0.f;
  float mrow = -1e30f, lsum = 0.f;

  const int nkt = (c >> 1) + 1;

#pragma unroll 1
  for (int kt = 0; kt < nkt; ++kt) {
    __builtin_amdgcn_sched_barrier(0);  // keep stage after prior tile's drained ds_reads
    // ---- stage K (swizzled rows) + V (16-wide panels) into LDS ----
#pragma unroll
    for (int i = 0; i < 8; ++i) {
      int c2 = i * 64 + lane;
      int r = c2 >> 3, g8 = (c2 & 7) ^ (r & 7);
      gld16(Kg + (size_t)(kt * 64 + r) * RS_ + g8 * 8, Ks + i * 512);
    }
#pragma unroll
    for (int i = 0; i < 8; ++i) {
      int c2 = i * 64 + lane;
      int p = c2 >> 7, k = (c2 >> 1) & 63, half = c2 & 1;
      gld16(Vg + (size_t)(kt * 64 + k) * RS_ + p * 16 + half * 8, Vs + i * 512);
    }
    asm volatile("s_waitcnt vmcnt(0)" ::: "memory");
    __builtin_amdgcn_sched_barrier(0);

    // ---- K fragments ----
    bf16x8 kf[2][4];
#pragma unroll
    for (int t = 0; t < 2; ++t)
#pragma unroll
      for (int d = 0; d < 4; ++d) {
        int row = 32 * t + l31;
        int col = ((d * 2 + hi) ^ (row & 7)) * 8;
        kf[t][d] = *(const bf16x8*)&Ks[row * 64 + col];
      }
    // ---- V fragments via transpose-read ----
    bf16x8 vf[2][4];
    {
      unsigned vb = lds_addr(Vs);
#pragma unroll
      for (int n2 = 0; n2 < 2; ++n2)
#pragma unroll
        for (int ks = 0; ks < 4; ++ks) {
          int p = 2 * n2 + (l31 >> 4);
          int k0 = ks * 16 + hi * 8;
          unsigned a = vb + p * 2048 + k0 * 32 + l15 * 8;
          i32x2 lo = tr64(a);
          i32x2 hi4 = tr64o(a);
          union { unsigned u[4]; bf16x8 v; } uu;
          uu.u[0] = (unsigned)lo[0]; uu.u[1] = (unsigned)lo[1];
          uu.u[2] = (unsigned)hi4[0]; uu.u[3] = (unsigned)hi4[1];
          vf[n2][ks] = uu.v;
        }
    }
    asm volatile("s_waitcnt lgkmcnt(0)" ::: "memory");
    __builtin_amdgcn_sched_barrier(0);

    // ---- S^T = K Q^T (lane = q col, rows = k via CROW) ----
    f32x16 st[2];
#pragma unroll
    for (int t = 0; t < 2; ++t) {
#pragma unroll
      for (int r = 0; r < 16; ++r) st[t][r] = 0.f;
#pragma unroll
      for (int d = 0; d < 4; ++d) st[t] = mfma32(kf[t][d], qf[d], st[t]);
    }
    if (kt == nkt - 1) {  // causal mask (only the diagonal tile can violate)
#pragma unroll
      for (int t = 0; t < 2; ++t)
#pragma unroll
        for (int r = 0; r < 16; ++r)
          if (kt * 64 + 32 * t + CROW(r) > q0 + l31) st[t][r] = -1e30f;
    }
    // ---- online softmax (exp2 domain), lane-local + 1 shfl ----
    float pm = -1e30f;
#pragma unroll
    for (int t = 0; t < 2; ++t)
#pragma unroll
      for (int r = 0; r < 16; ++r) pm = fmaxf(pm, st[t][r]);
    pm = fmaxf(pm, __shfl_xor(pm, 32));
    if (!__all(pm - mrow <= 11.0f)) {  // defer-max
      float mn = fmaxf(mrow, pm);
      float scl = exp2f(mrow - mn);
      mrow = mn;
      lsum *= scl;
#pragma unroll
      for (int r = 0; r < 16; ++r) {
        float sr = __shfl(scl, CROW(r));
        o[0][r] *= sr;
        o[1][r] *= sr;
      }
    }
    float ps = 0.f;
#pragma unroll
    for (int t = 0; t < 2; ++t)
#pragma unroll
      for (int r = 0; r < 16; ++r) {
        float e = exp2f(st[t][r] - mrow);
        st[t][r] = e;
        ps += e;
      }
    ps += __shfl_xor(ps, 32);
    lsum += ps;
    // ---- pack P, exchange cross-half, PV ----
    unsigned pk[2][8];
#pragma unroll
    for (int t = 0; t < 2; ++t)
#pragma unroll
      for (int j = 0; j < 8; ++j) pk[t][j] = pk2(st[t][2 * j], st[t][2 * j + 1]);
#pragma unroll
    for (int ks = 0; ks < 4; ++ks) {
      const int t = ks >> 1, rb = (ks & 1) * 4;
      unsigned s0 = hi ? pk[t][rb] : pk[t][rb + 2];
      unsigned s1 = hi ? pk[t][rb + 1] : pk[t][rb + 3];
      unsigned r0 = (unsigned)__shfl_xor((int)s0, 32);
      unsigned r1 = (unsigned)__shfl_xor((int)s1, 32);
      union { unsigned u[4]; bf16x8 v; } w;
      if (hi == 0) {
        w.u[0] = pk[t][rb]; w.u[1] = pk[t][rb + 1]; w.u[2] = r0; w.u[3] = r1;
      } else {
        w.u[0] = r0; w.u[1] = r1; w.u[2] = pk[t][rb + 2]; w.u[3] = pk[t][rb + 3];
      }
      o[0] = mfma32(w.v, vf[0][ks], o[0]);
      o[1] = mfma32(w.v, vf[1][ks], o[1]);
    }
  }

  // ---- epilogue ----
#pragma unroll
  for (int r = 0; r < 16; ++r) {
    float li = __shfl(lsum, CROW(r));
    float inv = 1.0f / li;
    int qrow = q0 + CROW(r);
#pragma unroll
    for (int n2 = 0; n2 < 2; ++n2)
      Cg[(size_t)qrow * D_ + n2 * 32 + l31] = (bf16_t)(o[n2][r] * inv);
  }
}

// ---------------- launch ----------------
extern "C" void kernel_launch(void* const* d_in, const int* in_sizes, int n_in,
                              void* d_out, int out_size, void* d_ws, size_t ws_size,
                              hipStream_t stream) {
  const float* x   = (const float*)d_in[0];
  const float* w_q = (const float*)d_in[1];
  const float* w_k = (const float*)d_in[2];
  const float* w_v = (const float*)d_in[3];
  const float* w_o = (const float*)d_in[4];

  const int M = B_ * T_;              // 4096
  const size_t XN = (size_t)M * D_;   // 4M
  const size_t WN = (size_t)D_ * D_;  // 1M

  bf16_t* ws = (bf16_t*)d_ws;
  bf16_t* xb   = ws;            // 4M
  bf16_t* wqb  = xb + XN;       // 3M (q,k,v) + 1M (o) contiguous
  bf16_t* wob  = wqb + 3 * WN;
  bf16_t* qkv  = wob + WN;      // [4096][3072] = 12M
  bf16_t* ctx  = qkv + (size_t)M * RS_;  // 4M

  cvt_x<<<(int)(XN / 4 / 256), 256, 0, stream>>>(x, xb, (int)(XN / 4));
  cvt_w4<<<dim3((int)(WN / 4 / 256), 4), 256, 0, stream>>>(w_q, w_k, w_v, w_o, wqb, (int)(WN / 4));

  // fused QKV GEMM: B = [w_q; w_k; w_v] (3072 x 1024), q-part pre-scaled (exp2 domain)
  gemm_nt<false, true><<<dim3(RS_ / 128, M / 128), 256, 0, stream>>>(xb, wqb, qkv, M, RS_, D_);

  attn_fwd<<<dim3(64, B_ * H_), 64, 0, stream>>>(qkv, ctx);

  gemm_nt<true, false><<<dim3(D_ / 128, M / 128), 256, 0, stream>>>(ctx, wob, d_out, M, D_, D_);
}

// Round 5
// 167.598 us; speedup vs baseline: 1.6223x; 1.0345x over previous
//
#include <hip/hip_runtime.h>
#include <hip/hip_bf16.h>

typedef __bf16 bf16_t;
typedef __attribute__((ext_vector_type(8))) __bf16 bf16x8;
typedef __attribute__((ext_vector_type(4))) __bf16 bf16x4;
typedef __attribute__((ext_vector_type(4))) float f32x4;
typedef __attribute__((ext_vector_type(16))) float f32x16;
typedef __attribute__((ext_vector_type(2))) int i32x2;

#define B_ 2
#define T_ 2048
#define D_ 1024
#define H_ 16
#define DH_ 64
#define RS_ 3072  // fused qkv row stride

static __device__ __forceinline__ f32x4 mfma16(bf16x8 a, bf16x8 b, f32x4 c) {
  return __builtin_amdgcn_mfma_f32_16x16x32_bf16(a, b, c, 0, 0, 0);
}
static __device__ __forceinline__ f32x16 mfma32(bf16x8 a, bf16x8 b, f32x16 c) {
  return __builtin_amdgcn_mfma_f32_32x32x16_bf16(a, b, c, 0, 0, 0);
}
static __device__ __forceinline__ void gld16(const bf16_t* g, bf16_t* l) {
  __builtin_amdgcn_global_load_lds(
      (const __attribute__((address_space(1))) unsigned int*)g,
      (__attribute__((address_space(3))) unsigned int*)l, 16, 0, 0);
}
static __device__ __forceinline__ unsigned lds_addr(const bf16_t* p) {
  return (unsigned)(uintptr_t)(const __attribute__((address_space(3))) bf16_t*)p;
}
static __device__ __forceinline__ i32x2 tr64(unsigned a) {
  i32x2 d;
  asm volatile("ds_read_b64_tr_b16 %0, %1" : "=v"(d) : "v"(a));
  return d;
}
static __device__ __forceinline__ i32x2 tr64o(unsigned a) {  // +128B (4 k-rows)
  i32x2 d;
  asm volatile("ds_read_b64_tr_b16 %0, %1 offset:128" : "=v"(d) : "v"(a));
  return d;
}
static __device__ __forceinline__ unsigned pk2(float lo, float hi2) {
  unsigned short a = __builtin_bit_cast(unsigned short, (bf16_t)lo);
  unsigned short b = __builtin_bit_cast(unsigned short, (bf16_t)hi2);
  return (unsigned)a | ((unsigned)b << 16);
}

// ---------------- fp32 -> bf16 conversion ----------------
__global__ __launch_bounds__(256) void cvt_x(const float* __restrict__ in,
                                             bf16_t* __restrict__ out, int n4) {
  int i = blockIdx.x * 256 + threadIdx.x;
  if (i >= n4) return;
  float4 f = reinterpret_cast<const float4*>(in)[i];
  bf16x4 o;
  o[0] = (bf16_t)f.x; o[1] = (bf16_t)f.y; o[2] = (bf16_t)f.z; o[3] = (bf16_t)f.w;
  reinterpret_cast<bf16x4*>(out)[i] = o;
}

__global__ __launch_bounds__(256) void cvt_w4(const float* __restrict__ w0,
                                              const float* __restrict__ w1,
                                              const float* __restrict__ w2,
                                              const float* __restrict__ w3,
                                              bf16_t* __restrict__ out, int n4each) {
  const float* in = blockIdx.y == 0 ? w0 : blockIdx.y == 1 ? w1 : blockIdx.y == 2 ? w2 : w3;
  bf16_t* o = out + (size_t)blockIdx.y * (size_t)n4each * 4;
  int i = blockIdx.x * 256 + threadIdx.x;
  if (i >= n4each) return;
  float4 f = reinterpret_cast<const float4*>(in)[i];
  bf16x4 v;
  v[0] = (bf16_t)f.x; v[1] = (bf16_t)f.y; v[2] = (bf16_t)f.z; v[3] = (bf16_t)f.w;
  reinterpret_cast<bf16x4*>(o)[i] = v;
}

// ---------------- NT GEMM: C = A * B^T, global_load_lds staging (m97) ----------------
template <bool STORE_F32, bool QSCALE>
__global__ __launch_bounds__(256) void gemm_nt(const bf16_t* __restrict__ A,
                                               const bf16_t* __restrict__ Bm,
                                               void* __restrict__ Cv,
                                               int M, int N, int K) {
  __shared__ __align__(16) bf16_t As[128 * 64];
  __shared__ __align__(16) bf16_t Bs[128 * 64];
  const int tid = threadIdx.x, lane = tid & 63, wave = tid >> 6;
  const int brow = blockIdx.y * 128, bcol = blockIdx.x * 128;
  const int row0 = (wave >> 1) * 64, col0 = (wave & 1) * 64;
  const int lrow = lane >> 3, lcol = (lane & 7) * 8;
  // q-part pre-scaled by (1/sqrt(DH)) * log2(e) -> softmax runs in exp2 domain
  const float cscale = (QSCALE && bcol < 1024) ? 0.18033688011112042f : 1.0f;

  f32x4 acc[4][4];
#pragma unroll
  for (int m = 0; m < 4; ++m)
#pragma unroll
    for (int n = 0; n < 4; ++n) acc[m][n] = f32x4{0.f, 0.f, 0.f, 0.f};

  for (int k0 = 0; k0 < K; k0 += 64) {
    const bf16_t* ga = A + (size_t)(brow + 32 * wave + lrow) * K + k0 + lcol;
    const bf16_t* gb = Bm + (size_t)(bcol + 32 * wave + lrow) * K + k0 + lcol;
#pragma unroll
    for (int s = 0; s < 4; ++s) {
      gld16(ga + (size_t)(8 * s) * K, &As[(32 * wave + 8 * s) * 64]);
      gld16(gb + (size_t)(8 * s) * K, &Bs[(32 * wave + 8 * s) * 64]);
    }
    __syncthreads();
#pragma unroll
    for (int kk = 0; kk < 2; ++kk) {
      const int ko = kk * 32 + (lane >> 4) * 8;
      bf16x8 af[4], bfr[4];
#pragma unroll
      for (int m = 0; m < 4; ++m)
        af[m] = *(const bf16x8*)&As[(row0 + 16 * m + (lane & 15)) * 64 + ko];
#pragma unroll
      for (int n = 0; n < 4; ++n)
        bfr[n] = *(const bf16x8*)&Bs[(col0 + 16 * n + (lane & 15)) * 64 + ko];
#pragma unroll
      for (int m = 0; m < 4; ++m)
#pragma unroll
        for (int n = 0; n < 4; ++n) acc[m][n] = mfma16(af[m], bfr[n], acc[m][n]);
    }
    __syncthreads();
  }
  const int crow = brow + row0 + (lane >> 4) * 4;
  const int ccol = bcol + col0 + (lane & 15);
#pragma unroll
  for (int m = 0; m < 4; ++m)
#pragma unroll
    for (int n = 0; n < 4; ++n)
#pragma unroll
      for (int r = 0; r < 4; ++r) {
        size_t idx = (size_t)(crow + 16 * m + r) * N + (ccol + 16 * n);
        float v = acc[m][n][r] * cscale;
        if (STORE_F32) reinterpret_cast<float*>(Cv)[idx] = v;
        else reinterpret_cast<bf16_t*>(Cv)[idx] = (bf16_t)v;
      }
}

// ---------------- causal flash attention ----------------
// Block = 128 thr (2 waves). Wave wv owns q-chunk c = 2*pr + wv (32 rows); both
// chunks need exactly pr+1 K-tiles, so K/V staging is shared (each wave stages half)
// and double-buffered: one __syncthreads per tile drains the PREVIOUS prefetch
// (implicit vmcnt(0)), then next tile's stage is issued before compute.
#define CROW(r) ((((r) & 3) + 8 * ((r) >> 2)) + 4 * hi)

__global__ __launch_bounds__(128, 2) void attn_fwd(const bf16_t* __restrict__ qkv,
                                                   bf16_t* __restrict__ ctx) {
  __shared__ __align__(128) bf16_t Ks[2][64 * 64];      // row-major, 8-elem XOR swizzle
  __shared__ __align__(128) bf16_t Vs[2][4 * 64 * 16];  // 16-wide panels for tr_b16
  const int tid = threadIdx.x;
  const int lane = tid & 63;
  const int wv = tid >> 6;
  // work-hash: spreads chunk lengths across CUs under round-robin dispatch
  const int pr = ((int)blockIdx.x + (int)blockIdx.y) & 31;
  const int c = 2 * pr + wv;  // q-chunk: rows 32c..32c+31
  const int bh = blockIdx.y;
  const int b = bh >> 4, h = bh & 15;
  const bf16_t* Qg = qkv + (size_t)b * T_ * RS_ + h * DH_;
  const bf16_t* Kg = Qg + 1024;
  const bf16_t* Vg = Qg + 2048;
  bf16_t* Cg = ctx + (size_t)b * T_ * D_ + h * DH_;

  const int hi = lane >> 5;
  const int l31 = lane & 31;
  const int l15 = lane & 15;
  const int q0 = c * 32;
  const int nkt = pr + 1;

  // Q fragments (exp2-domain pre-scaled), kept in regs
  bf16x8 qf[4];
#pragma unroll
  for (int d = 0; d < 4; ++d)
    qf[d] = *(const bf16x8*)&Qg[(size_t)(q0 + l31) * RS_ + d * 16 + hi * 8];

  f32x16 o[2];
#pragma unroll
  for (int n = 0; n < 2; ++n)
#pragma unroll
    for (int r = 0; r < 16; ++r) o[n][r] = 0.f;
  float mrow = -1e30f, lsum = 0.f;

  // shared staging: 16 gld16 total per tile, each wave issues 8.
  auto stage = [&](int bi, int kt) {
#pragma unroll
    for (int i = 0; i < 4; ++i) {
      int c2 = i * 128 + tid;
      int r = c2 >> 3, g8 = (c2 & 7) ^ (r & 7);
      gld16(Kg + (size_t)(kt * 64 + r) * RS_ + g8 * 8, &Ks[bi][i * 1024 + wv * 512]);
    }
#pragma unroll
    for (int i = 0; i < 4; ++i) {
      int c2 = i * 128 + tid;
      int pn = c2 >> 7, k = (c2 >> 1) & 63, half = c2 & 1;
      gld16(Vg + (size_t)(kt * 64 + k) * RS_ + pn * 16 + half * 8, &Vs[bi][i * 1024 + wv * 512]);
    }
  };
  stage(0, 0);
  int buf = 0;

#pragma unroll 1
  for (int kt = 0; kt < nkt; ++kt) {
    // drains prefetch (implicit vmcnt(0) lgkmcnt(0)) + cross-wave staging visible
    __syncthreads();
    if (kt + 1 < nkt) stage(buf ^ 1, kt + 1);  // async prefetch, waited next iter

    // ---- K fragments ----
    bf16x8 kf[2][4];
#pragma unroll
    for (int t = 0; t < 2; ++t)
#pragma unroll
      for (int d = 0; d < 4; ++d) {
        int row = 32 * t + l31;
        int col = ((d * 2 + hi) ^ (row & 7)) * 8;
        kf[t][d] = *(const bf16x8*)&Ks[buf][row * 64 + col];
      }
    // ---- V fragments via transpose-read ----
    bf16x8 vf[2][4];
    {
      unsigned vb = lds_addr(&Vs[buf][0]);
#pragma unroll
      for (int n2 = 0; n2 < 2; ++n2)
#pragma unroll
        for (int ks = 0; ks < 4; ++ks) {
          int pn = 2 * n2 + (l31 >> 4);
          int k0 = ks * 16 + hi * 8;
          unsigned a = vb + pn * 2048 + k0 * 32 + l15 * 8;
          i32x2 lo = tr64(a);
          i32x2 hi4 = tr64o(a);
          union { unsigned u[4]; bf16x8 v; } uu;
          uu.u[0] = (unsigned)lo[0]; uu.u[1] = (unsigned)lo[1];
          uu.u[2] = (unsigned)hi4[0]; uu.u[3] = (unsigned)hi4[1];
          vf[n2][ks] = uu.v;
        }
    }
    asm volatile("s_waitcnt lgkmcnt(0)" ::: "memory");
    __builtin_amdgcn_sched_barrier(0);

    // ---- S^T = K Q^T (lane = q col, rows = k via CROW) ----
    f32x16 st[2];
#pragma unroll
    for (int t = 0; t < 2; ++t) {
#pragma unroll
      for (int r = 0; r < 16; ++r) st[t][r] = 0.f;
#pragma unroll
      for (int d = 0; d < 4; ++d) st[t] = mfma32(kf[t][d], qf[d], st[t]);
    }
    if (kt == nkt - 1) {  // causal mask (only the diagonal tile can violate)
#pragma unroll
      for (int t = 0; t < 2; ++t)
#pragma unroll
        for (int r = 0; r < 16; ++r)
          if (kt * 64 + 32 * t + CROW(r) > q0 + l31) st[t][r] = -1e30f;
    }
    // ---- online softmax (exp2 domain), lane-local + 1 shfl ----
    float pm = -1e30f;
#pragma unroll
    for (int t = 0; t < 2; ++t)
#pragma unroll
      for (int r = 0; r < 16; ++r) pm = fmaxf(pm, st[t][r]);
    pm = fmaxf(pm, __shfl_xor(pm, 32));
    if (!__all(pm - mrow <= 11.0f)) {  // defer-max
      float mn = fmaxf(mrow, pm);
      float scl = exp2f(mrow - mn);
      mrow = mn;
      lsum *= scl;
#pragma unroll
      for (int r = 0; r < 16; ++r) {
        float sr = __shfl(scl, CROW(r));
        o[0][r] *= sr;
        o[1][r] *= sr;
      }
    }
    float ps = 0.f;
#pragma unroll
    for (int t = 0; t < 2; ++t)
#pragma unroll
      for (int r = 0; r < 16; ++r) {
        float e = exp2f(st[t][r] - mrow);
        st[t][r] = e;
        ps += e;
      }
    ps += __shfl_xor(ps, 32);
    lsum += ps;
    // ---- pack P, exchange cross-half, PV ----
    unsigned pk[2][8];
#pragma unroll
    for (int t = 0; t < 2; ++t)
#pragma unroll
      for (int j = 0; j < 8; ++j) pk[t][j] = pk2(st[t][2 * j], st[t][2 * j + 1]);
#pragma unroll
    for (int ks = 0; ks < 4; ++ks) {
      const int t = ks >> 1, rb = (ks & 1) * 4;
      unsigned s0 = hi ? pk[t][rb] : pk[t][rb + 2];
      unsigned s1 = hi ? pk[t][rb + 1] : pk[t][rb + 3];
      unsigned r0 = (unsigned)__shfl_xor((int)s0, 32);
      unsigned r1 = (unsigned)__shfl_xor((int)s1, 32);
      union { unsigned u[4]; bf16x8 v; } w;
      if (hi == 0) {
        w.u[0] = pk[t][rb]; w.u[1] = pk[t][rb + 1]; w.u[2] = r0; w.u[3] = r1;
      } else {
        w.u[0] = r0; w.u[1] = r1; w.u[2] = pk[t][rb + 2]; w.u[3] = pk[t][rb + 3];
      }
      o[0] = mfma32(w.v, vf[0][ks], o[0]);
      o[1] = mfma32(w.v, vf[1][ks], o[1]);
    }
    buf ^= 1;
  }

  // ---- epilogue ----
#pragma unroll
  for (int r = 0; r < 16; ++r) {
    float li = __shfl(lsum, CROW(r));
    float inv = 1.0f / li;
    int qrow = q0 + CROW(r);
#pragma unroll
    for (int n2 = 0; n2 < 2; ++n2)
      Cg[(size_t)qrow * D_ + n2 * 32 + l31] = (bf16_t)(o[n2][r] * inv);
  }
}

// ---------------- launch ----------------
extern "C" void kernel_launch(void* const* d_in, const int* in_sizes, int n_in,
                              void* d_out, int out_size, void* d_ws, size_t ws_size,
                              hipStream_t stream) {
  const float* x   = (const float*)d_in[0];
  const float* w_q = (const float*)d_in[1];
  const float* w_k = (const float*)d_in[2];
  const float* w_v = (const float*)d_in[3];
  const float* w_o = (const float*)d_in[4];

  const int M = B_ * T_;              // 4096
  const size_t XN = (size_t)M * D_;   // 4M
  const size_t WN = (size_t)D_ * D_;  // 1M

  bf16_t* ws = (bf16_t*)d_ws;
  bf16_t* xb   = ws;            // 4M
  bf16_t* wqb  = xb + XN;       // 3M (q,k,v) + 1M (o) contiguous
  bf16_t* wob  = wqb + 3 * WN;
  bf16_t* qkv  = wob + WN;      // [4096][3072] = 12M
  bf16_t* ctx  = qkv + (size_t)M * RS_;  // 4M

  cvt_x<<<(int)(XN / 4 / 256), 256, 0, stream>>>(x, xb, (int)(XN / 4));
  cvt_w4<<<dim3((int)(WN / 4 / 256), 4), 256, 0, stream>>>(w_q, w_k, w_v, w_o, wqb, (int)(WN / 4));

  // fused QKV GEMM: B = [w_q; w_k; w_v] (3072 x 1024), q-part pre-scaled (exp2 domain)
  gemm_nt<false, true><<<dim3(RS_ / 128, M / 128), 256, 0, stream>>>(xb, wqb, qkv, M, RS_, D_);

  attn_fwd<<<dim3(32, B_ * H_), 128, 0, stream>>>(qkv, ctx);

  gemm_nt<true, false><<<dim3(D_ / 128, M / 128), 256, 0, stream>>>(ctx, wob, d_out, M, D_, D_);
}

// Round 6
// 156.093 us; speedup vs baseline: 1.7418x; 1.0737x over previous
//
#include <hip/hip_runtime.h>
#include <hip/hip_bf16.h>

typedef __bf16 bf16_t;
typedef __attribute__((ext_vector_type(8))) __bf16 bf16x8;
typedef __attribute__((ext_vector_type(4))) __bf16 bf16x4;
typedef __attribute__((ext_vector_type(4))) float f32x4;
typedef __attribute__((ext_vector_type(16))) float f32x16;
typedef __attribute__((ext_vector_type(2))) int i32x2;

#define B_ 2
#define T_ 2048
#define D_ 1024
#define H_ 16
#define DH_ 64
#define RS_ 3072  // fused qkv row stride

static __device__ __forceinline__ f32x4 mfma16(bf16x8 a, bf16x8 b, f32x4 c) {
  return __builtin_amdgcn_mfma_f32_16x16x32_bf16(a, b, c, 0, 0, 0);
}
static __device__ __forceinline__ f32x16 mfma32(bf16x8 a, bf16x8 b, f32x16 c) {
  return __builtin_amdgcn_mfma_f32_32x32x16_bf16(a, b, c, 0, 0, 0);
}
static __device__ __forceinline__ void gld16(const bf16_t* g, bf16_t* l) {
  __builtin_amdgcn_global_load_lds(
      (const __attribute__((address_space(1))) unsigned int*)g,
      (__attribute__((address_space(3))) unsigned int*)l, 16, 0, 0);
}
static __device__ __forceinline__ unsigned lds_addr(const bf16_t* p) {
  return (unsigned)(uintptr_t)(const __attribute__((address_space(3))) bf16_t*)p;
}
static __device__ __forceinline__ i32x2 tr64(unsigned a) {
  i32x2 d;
  asm volatile("ds_read_b64_tr_b16 %0, %1" : "=v"(d) : "v"(a));
  return d;
}
static __device__ __forceinline__ i32x2 tr64o(unsigned a) {  // +128B (4 k-rows)
  i32x2 d;
  asm volatile("ds_read_b64_tr_b16 %0, %1 offset:128" : "=v"(d) : "v"(a));
  return d;
}
static __device__ __forceinline__ unsigned pk2(float lo, float hi2) {
  unsigned short a = __builtin_bit_cast(unsigned short, (bf16_t)lo);
  unsigned short b = __builtin_bit_cast(unsigned short, (bf16_t)hi2);
  return (unsigned)a | ((unsigned)b << 16);
}

#define WAITV4 { asm volatile("s_waitcnt vmcnt(4)" ::: "memory"); __builtin_amdgcn_sched_barrier(0); }
#define WAITV0 { asm volatile("s_waitcnt vmcnt(0)" ::: "memory"); __builtin_amdgcn_sched_barrier(0); }
#define BAR    { __builtin_amdgcn_s_barrier(); __builtin_amdgcn_sched_barrier(0); }

// ---------------- fp32 -> bf16 conversion ----------------
__global__ __launch_bounds__(256) void cvt_x(const float* __restrict__ in,
                                             bf16_t* __restrict__ out, int n4) {
  int i = blockIdx.x * 256 + threadIdx.x;
  if (i >= n4) return;
  float4 f = reinterpret_cast<const float4*>(in)[i];
  bf16x4 o;
  o[0] = (bf16_t)f.x; o[1] = (bf16_t)f.y; o[2] = (bf16_t)f.z; o[3] = (bf16_t)f.w;
  reinterpret_cast<bf16x4*>(out)[i] = o;
}

__global__ __launch_bounds__(256) void cvt_w4(const float* __restrict__ w0,
                                              const float* __restrict__ w1,
                                              const float* __restrict__ w2,
                                              const float* __restrict__ w3,
                                              bf16_t* __restrict__ out, int n4each) {
  const float* in = blockIdx.y == 0 ? w0 : blockIdx.y == 1 ? w1 : blockIdx.y == 2 ? w2 : w3;
  bf16_t* o = out + (size_t)blockIdx.y * (size_t)n4each * 4;
  int i = blockIdx.x * 256 + threadIdx.x;
  if (i >= n4each) return;
  float4 f = reinterpret_cast<const float4*>(in)[i];
  bf16x4 v;
  v[0] = (bf16_t)f.x; v[1] = (bf16_t)f.y; v[2] = (bf16_t)f.z; v[3] = (bf16_t)f.w;
  reinterpret_cast<bf16x4*>(o)[i] = v;
}

// ---------------- NT GEMM: C = A * B^T, global_load_lds staging (m97) ----------------
template <bool STORE_F32, bool QSCALE>
__global__ __launch_bounds__(256) void gemm_nt(const bf16_t* __restrict__ A,
                                               const bf16_t* __restrict__ Bm,
                                               void* __restrict__ Cv,
                                               int M, int N, int K) {
  __shared__ __align__(16) bf16_t As[128 * 64];
  __shared__ __align__(16) bf16_t Bs[128 * 64];
  const int tid = threadIdx.x, lane = tid & 63, wave = tid >> 6;
  const int brow = blockIdx.y * 128, bcol = blockIdx.x * 128;
  const int row0 = (wave >> 1) * 64, col0 = (wave & 1) * 64;
  const int lrow = lane >> 3, lcol = (lane & 7) * 8;
  // q-part pre-scaled by (1/sqrt(DH)) * log2(e) -> softmax runs in exp2 domain
  const float cscale = (QSCALE && bcol < 1024) ? 0.18033688011112042f : 1.0f;

  f32x4 acc[4][4];
#pragma unroll
  for (int m = 0; m < 4; ++m)
#pragma unroll
    for (int n = 0; n < 4; ++n) acc[m][n] = f32x4{0.f, 0.f, 0.f, 0.f};

  for (int k0 = 0; k0 < K; k0 += 64) {
    const bf16_t* ga = A + (size_t)(brow + 32 * wave + lrow) * K + k0 + lcol;
    const bf16_t* gb = Bm + (size_t)(bcol + 32 * wave + lrow) * K + k0 + lcol;
#pragma unroll
    for (int s = 0; s < 4; ++s) {
      gld16(ga + (size_t)(8 * s) * K, &As[(32 * wave + 8 * s) * 64]);
      gld16(gb + (size_t)(8 * s) * K, &Bs[(32 * wave + 8 * s) * 64]);
    }
    __syncthreads();
#pragma unroll
    for (int kk = 0; kk < 2; ++kk) {
      const int ko = kk * 32 + (lane >> 4) * 8;
      bf16x8 af[4], bfr[4];
#pragma unroll
      for (int m = 0; m < 4; ++m)
        af[m] = *(const bf16x8*)&As[(row0 + 16 * m + (lane & 15)) * 64 + ko];
#pragma unroll
      for (int n = 0; n < 4; ++n)
        bfr[n] = *(const bf16x8*)&Bs[(col0 + 16 * n + (lane & 15)) * 64 + ko];
#pragma unroll
      for (int m = 0; m < 4; ++m)
#pragma unroll
        for (int n = 0; n < 4; ++n) acc[m][n] = mfma16(af[m], bfr[n], acc[m][n]);
    }
    __syncthreads();
  }
  const int crow = brow + row0 + (lane >> 4) * 4;
  const int ccol = bcol + col0 + (lane & 15);
#pragma unroll
  for (int m = 0; m < 4; ++m)
#pragma unroll
    for (int n = 0; n < 4; ++n)
#pragma unroll
      for (int r = 0; r < 4; ++r) {
        size_t idx = (size_t)(crow + 16 * m + r) * N + (ccol + 16 * n);
        float v = acc[m][n][r] * cscale;
        if (STORE_F32) reinterpret_cast<float*>(Cv)[idx] = v;
        else reinterpret_cast<bf16_t*>(Cv)[idx] = (bf16_t)v;
      }
}

// ---------------- causal flash attention ----------------
// Block = 256 thr (4 waves), grid (32 bh, 8 p) -> 256 blocks, 1/CU, all equal-length:
//   phase A: wave w owns chunk 4p+w    (block stages 2p+2 tiles)
//   phase B: wave w owns chunk 63-4p-w (block stages 32-2p tiles)
// Every wave = 33 compute tiles; every block = 34 staged tiles -> zero tail imbalance.
// Triple-buffered K/V, raw s_barrier + counted vmcnt(4): prefetch never drains.
#define CROW(r) ((((r) & 3) + 8 * ((r) >> 2)) + 4 * hi)

__global__ __launch_bounds__(256, 1) void attn_fwd(const bf16_t* __restrict__ qkv,
                                                   bf16_t* __restrict__ ctx) {
  __shared__ __align__(128) bf16_t KV[3][2][64 * 64];  // [buf][K|V][4096] = 48 KB
  const int tid = threadIdx.x;
  const int lane = tid & 63;
  const int wv = tid >> 6;
  const int bh = blockIdx.x, p = blockIdx.y;
  const int b = bh >> 4, h = bh & 15;
  const bf16_t* Qg = qkv + (size_t)b * T_ * RS_ + h * DH_;
  const bf16_t* Kg = Qg + 1024;
  const bf16_t* Vg = Qg + 2048;
  bf16_t* Cg = ctx + (size_t)b * T_ * D_ + h * DH_;

  const int hi = lane >> 5;
  const int l31 = lane & 31;
  const int l15 = lane & 15;

  // cooperative staging of one 64-key tile (K swizzled rows, V 16-wide panels)
  auto stage = [&](int bi, int kt) {
    bf16_t* Kb = &KV[bi][0][0];
    bf16_t* Vb = &KV[bi][1][0];
#pragma unroll
    for (int i = 0; i < 2; ++i) {
      int c2 = i * 256 + tid;
      int r = c2 >> 3, g8 = (c2 & 7) ^ (r & 7);
      gld16(Kg + (size_t)(kt * 64 + r) * RS_ + g8 * 8, Kb + i * 2048 + wv * 512);
    }
#pragma unroll
    for (int i = 0; i < 2; ++i) {
      int c2 = i * 256 + tid;
      int pn = c2 >> 7, k = (c2 >> 1) & 63, half = c2 & 1;
      gld16(Vg + (size_t)(kt * 64 + k) * RS_ + pn * 16 + half * 8, Vb + i * 2048 + wv * 512);
    }
  };

#pragma unroll 1
  for (int phase = 0; phase < 2; ++phase) {
    const int c = phase ? (63 - 4 * p - wv) : (4 * p + wv);
    const int q0 = c * 32;
    const int mynkt = (c >> 1) + 1;
    const int maxnkt = phase ? (32 - 2 * p) : (2 * p + 2);

    BAR;  // previous phase's LDS reads fully retired before re-staging
    stage(0, 0);
    stage(1, 1);

    // Q fragments (exp2-domain pre-scaled), regs for whole phase
    bf16x8 qf[4];
#pragma unroll
    for (int d = 0; d < 4; ++d)
      qf[d] = *(const bf16x8*)&Qg[(size_t)(q0 + l31) * RS_ + d * 16 + hi * 8];

    f32x16 o[2];
#pragma unroll
    for (int n = 0; n < 2; ++n)
#pragma unroll
      for (int r = 0; r < 16; ++r) o[n][r] = 0.f;
    float mrow = -1e30f, lsum = 0.f;

#pragma unroll 1
    for (int kt = 0; kt < maxnkt; ++kt) {
      // wait own slice of tile kt (leave tile kt+1's 4 loads in flight), then sync
      if (kt + 1 < maxnkt) { WAITV4 } else { WAITV0 }
      BAR;
      if (kt + 2 < maxnkt) stage((kt + 2) % 3, kt + 2);  // issued AFTER barrier: race-free

      if (kt < mynkt) {
        const bf16_t* Kb = &KV[kt % 3][0][0];
        // ---- K fragments ----
        bf16x8 kf[2][4];
#pragma unroll
        for (int t = 0; t < 2; ++t)
#pragma unroll
          for (int d = 0; d < 4; ++d) {
            int row = 32 * t + l31;
            int col = ((d * 2 + hi) ^ (row & 7)) * 8;
            kf[t][d] = *(const bf16x8*)&Kb[row * 64 + col];
          }
        // ---- V fragments via transpose-read ----
        bf16x8 vf[2][4];
        {
          unsigned vb = lds_addr(&KV[kt % 3][1][0]);
#pragma unroll
          for (int n2 = 0; n2 < 2; ++n2)
#pragma unroll
            for (int ks = 0; ks < 4; ++ks) {
              int pn = 2 * n2 + (l31 >> 4);
              int k0 = ks * 16 + hi * 8;
              unsigned a = vb + pn * 2048 + k0 * 32 + l15 * 8;
              i32x2 lo = tr64(a);
              i32x2 hi4 = tr64o(a);
              union { unsigned u[4]; bf16x8 v; } uu;
              uu.u[0] = (unsigned)lo[0]; uu.u[1] = (unsigned)lo[1];
              uu.u[2] = (unsigned)hi4[0]; uu.u[3] = (unsigned)hi4[1];
              vf[n2][ks] = uu.v;
            }
        }
        asm volatile("s_waitcnt lgkmcnt(0)" ::: "memory");
        __builtin_amdgcn_sched_barrier(0);

        // ---- S^T = K Q^T ----
        f32x16 st[2];
#pragma unroll
        for (int t = 0; t < 2; ++t) {
#pragma unroll
          for (int r = 0; r < 16; ++r) st[t][r] = 0.f;
#pragma unroll
          for (int d = 0; d < 4; ++d) st[t] = mfma32(kf[t][d], qf[d], st[t]);
        }
        if (kt == mynkt - 1) {  // diagonal tile: causal mask
#pragma unroll
          for (int t = 0; t < 2; ++t)
#pragma unroll
            for (int r = 0; r < 16; ++r)
              if (kt * 64 + 32 * t + CROW(r) > q0 + l31) st[t][r] = -1e30f;
        }
        // ---- online softmax (exp2 domain) ----
        float pm = -1e30f;
#pragma unroll
        for (int t = 0; t < 2; ++t)
#pragma unroll
          for (int r = 0; r < 16; ++r) pm = fmaxf(pm, st[t][r]);
        pm = fmaxf(pm, __shfl_xor(pm, 32));
        if (!__all(pm - mrow <= 11.0f)) {  // defer-max
          float mn = fmaxf(mrow, pm);
          float scl = exp2f(mrow - mn);
          mrow = mn;
          lsum *= scl;
#pragma unroll
          for (int r = 0; r < 16; ++r) {
            float sr = __shfl(scl, CROW(r));
            o[0][r] *= sr;
            o[1][r] *= sr;
          }
        }
        float ps = 0.f;
#pragma unroll
        for (int t = 0; t < 2; ++t)
#pragma unroll
          for (int r = 0; r < 16; ++r) {
            float e = exp2f(st[t][r] - mrow);
            st[t][r] = e;
            ps += e;
          }
        ps += __shfl_xor(ps, 32);
        lsum += ps;
        // ---- pack P, cross-half exchange, PV ----
        unsigned pk[2][8];
#pragma unroll
        for (int t = 0; t < 2; ++t)
#pragma unroll
          for (int j = 0; j < 8; ++j) pk[t][j] = pk2(st[t][2 * j], st[t][2 * j + 1]);
#pragma unroll
        for (int ks = 0; ks < 4; ++ks) {
          const int t = ks >> 1, rb = (ks & 1) * 4;
          unsigned s0 = hi ? pk[t][rb] : pk[t][rb + 2];
          unsigned s1 = hi ? pk[t][rb + 1] : pk[t][rb + 3];
          unsigned r0 = (unsigned)__shfl_xor((int)s0, 32);
          unsigned r1 = (unsigned)__shfl_xor((int)s1, 32);
          union { unsigned u[4]; bf16x8 v; } w;
          if (hi == 0) {
            w.u[0] = pk[t][rb]; w.u[1] = pk[t][rb + 1]; w.u[2] = r0; w.u[3] = r1;
          } else {
            w.u[0] = r0; w.u[1] = r1; w.u[2] = pk[t][rb + 2]; w.u[3] = pk[t][rb + 3];
          }
          o[0] = mfma32(w.v, vf[0][ks], o[0]);
          o[1] = mfma32(w.v, vf[1][ks], o[1]);
        }
      }  // compute guard
    }  // kt

    // ---- phase epilogue ----
#pragma unroll
    for (int r = 0; r < 16; ++r) {
      float li = __shfl(lsum, CROW(r));
      float inv = 1.0f / li;
      int qrow = q0 + CROW(r);
#pragma unroll
      for (int n2 = 0; n2 < 2; ++n2)
        Cg[(size_t)qrow * D_ + n2 * 32 + l31] = (bf16_t)(o[n2][r] * inv);
    }
  }  // phase
}

// ---------------- launch ----------------
extern "C" void kernel_launch(void* const* d_in, const int* in_sizes, int n_in,
                              void* d_out, int out_size, void* d_ws, size_t ws_size,
                              hipStream_t stream) {
  const float* x   = (const float*)d_in[0];
  const float* w_q = (const float*)d_in[1];
  const float* w_k = (const float*)d_in[2];
  const float* w_v = (const float*)d_in[3];
  const float* w_o = (const float*)d_in[4];

  const int M = B_ * T_;              // 4096
  const size_t XN = (size_t)M * D_;   // 4M
  const size_t WN = (size_t)D_ * D_;  // 1M

  bf16_t* ws = (bf16_t*)d_ws;
  bf16_t* xb   = ws;            // 4M
  bf16_t* wqb  = xb + XN;       // 3M (q,k,v) + 1M (o) contiguous
  bf16_t* wob  = wqb + 3 * WN;
  bf16_t* qkv  = wob + WN;      // [4096][3072] = 12M
  bf16_t* ctx  = qkv + (size_t)M * RS_;  // 4M

  cvt_x<<<(int)(XN / 4 / 256), 256, 0, stream>>>(x, xb, (int)(XN / 4));
  cvt_w4<<<dim3((int)(WN / 4 / 256), 4), 256, 0, stream>>>(w_q, w_k, w_v, w_o, wqb, (int)(WN / 4));

  // fused QKV GEMM: B = [w_q; w_k; w_v] (3072 x 1024), q-part pre-scaled (exp2 domain)
  gemm_nt<false, true><<<dim3(RS_ / 128, M / 128), 256, 0, stream>>>(xb, wqb, qkv, M, RS_, D_);

  attn_fwd<<<dim3(B_ * H_, 8), 256, 0, stream>>>(qkv, ctx);

  gemm_nt<true, false><<<dim3(D_ / 128, M / 128), 256, 0, stream>>>(ctx, wob, d_out, M, D_, D_);
}

// Round 7
// 138.875 us; speedup vs baseline: 1.9578x; 1.1240x over previous
//
#include <hip/hip_runtime.h>
#include <hip/hip_bf16.h>

typedef __bf16 bf16_t;
typedef __attribute__((ext_vector_type(8))) __bf16 bf16x8;
typedef __attribute__((ext_vector_type(4))) __bf16 bf16x4;
typedef __attribute__((ext_vector_type(4))) float f32x4;
typedef __attribute__((ext_vector_type(16))) float f32x16;
typedef __attribute__((ext_vector_type(2))) int i32x2;

#define B_ 2
#define T_ 2048
#define D_ 1024
#define H_ 16
#define DH_ 64
#define RS_ 3072  // fused qkv row stride

static __device__ __forceinline__ f32x4 mfma16(bf16x8 a, bf16x8 b, f32x4 c) {
  return __builtin_amdgcn_mfma_f32_16x16x32_bf16(a, b, c, 0, 0, 0);
}
static __device__ __forceinline__ f32x16 mfma32(bf16x8 a, bf16x8 b, f32x16 c) {
  return __builtin_amdgcn_mfma_f32_32x32x16_bf16(a, b, c, 0, 0, 0);
}
static __device__ __forceinline__ void gld16(const bf16_t* g, bf16_t* l) {
  __builtin_amdgcn_global_load_lds(
      (const __attribute__((address_space(1))) unsigned int*)g,
      (__attribute__((address_space(3))) unsigned int*)l, 16, 0, 0);
}
static __device__ __forceinline__ unsigned lds_addr(const bf16_t* p) {
  return (unsigned)(uintptr_t)(const __attribute__((address_space(3))) bf16_t*)p;
}
static __device__ __forceinline__ i32x2 tr64(unsigned a) {
  i32x2 d;
  asm volatile("ds_read_b64_tr_b16 %0, %1" : "=v"(d) : "v"(a));
  return d;
}
static __device__ __forceinline__ i32x2 tr64o(unsigned a) {  // +128B (4 k-rows)
  i32x2 d;
  asm volatile("ds_read_b64_tr_b16 %0, %1 offset:128" : "=v"(d) : "v"(a));
  return d;
}
static __device__ __forceinline__ unsigned pk2(float lo, float hi2) {
  unsigned short a = __builtin_bit_cast(unsigned short, (bf16_t)lo);
  unsigned short b = __builtin_bit_cast(unsigned short, (bf16_t)hi2);
  return (unsigned)a | ((unsigned)b << 16);
}

#define WAITV4 { asm volatile("s_waitcnt vmcnt(4)" ::: "memory"); __builtin_amdgcn_sched_barrier(0); }
#define WAITV0 { asm volatile("s_waitcnt vmcnt(0)" ::: "memory"); __builtin_amdgcn_sched_barrier(0); }
#define BAR    { __builtin_amdgcn_s_barrier(); __builtin_amdgcn_sched_barrier(0); }
#define WAITL0 { asm volatile("s_waitcnt lgkmcnt(0)" ::: "memory"); __builtin_amdgcn_sched_barrier(0); }

// ---------------- fp32 -> bf16 conversion ----------------
__global__ __launch_bounds__(256) void cvt_x(const float* __restrict__ in,
                                             bf16_t* __restrict__ out, int n4) {
  int i = blockIdx.x * 256 + threadIdx.x;
  if (i >= n4) return;
  float4 f = reinterpret_cast<const float4*>(in)[i];
  bf16x4 o;
  o[0] = (bf16_t)f.x; o[1] = (bf16_t)f.y; o[2] = (bf16_t)f.z; o[3] = (bf16_t)f.w;
  reinterpret_cast<bf16x4*>(out)[i] = o;
}

__global__ __launch_bounds__(256) void cvt_w4(const float* __restrict__ w0,
                                              const float* __restrict__ w1,
                                              const float* __restrict__ w2,
                                              const float* __restrict__ w3,
                                              bf16_t* __restrict__ out, int n4each) {
  const float* in = blockIdx.y == 0 ? w0 : blockIdx.y == 1 ? w1 : blockIdx.y == 2 ? w2 : w3;
  bf16_t* o = out + (size_t)blockIdx.y * (size_t)n4each * 4;
  int i = blockIdx.x * 256 + threadIdx.x;
  if (i >= n4each) return;
  float4 f = reinterpret_cast<const float4*>(in)[i];
  bf16x4 v;
  v[0] = (bf16_t)f.x; v[1] = (bf16_t)f.y; v[2] = (bf16_t)f.z; v[3] = (bf16_t)f.w;
  reinterpret_cast<bf16x4*>(o)[i] = v;
}

// ---------------- NT GEMM: C = A * B^T ----------------
// Triple-buffered BK=32 pipeline (same counted-vmcnt structure as attn_fwd):
// per step {vmcnt(4); s_barrier; stage(k+2); ds_read; lgkmcnt(0); 16 MFMA}.
// Prefetch has a full compute phase + barrier to land -> no exposed drain.
// LDS 48KB -> 3 blocks/CU.
template <bool STORE_F32, bool QSCALE>
__global__ __launch_bounds__(256) void gemm_nt(const bf16_t* __restrict__ A,
                                               const bf16_t* __restrict__ Bm,
                                               void* __restrict__ Cv,
                                               int M, int N, int K) {
  __shared__ __align__(16) bf16_t As[3][128 * 32];
  __shared__ __align__(16) bf16_t Bs[3][128 * 32];
  const int tid = threadIdx.x, lane = tid & 63, wave = tid >> 6;
  const int l15 = lane & 15;
  const int brow = blockIdx.y * 128, bcol = blockIdx.x * 128;
  const int row0 = (wave >> 1) * 64, col0 = (wave & 1) * 64;
  const float cscale = (QSCALE && bcol < 1024) ? 0.18033688011112042f : 1.0f;

  f32x4 acc[4][4];
#pragma unroll
  for (int m = 0; m < 4; ++m)
#pragma unroll
    for (int n = 0; n < 4; ++n) acc[m][n] = f32x4{0.f, 0.f, 0.f, 0.f};

  const int nst = K >> 5;  // K/32 steps
  const int srow = tid >> 2;            // 0..63 (source row within half-tile)
  const int sc8 = (tid & 3) * 8;        // source col granule
  // per-step staging: 2 gld16 for A + 2 for B per thread (4 in flight per step)
  auto stage = [&](int bi, int ks) {
    const int k0 = ks * 32;
#pragma unroll
    for (int i = 0; i < 2; ++i)
      gld16(A + (size_t)(brow + 64 * i + srow) * K + k0 + sc8,
            &As[bi][2048 * i + 512 * wave]);
#pragma unroll
    for (int i = 0; i < 2; ++i)
      gld16(Bm + (size_t)(bcol + 64 * i + srow) * K + k0 + sc8,
            &Bs[bi][2048 * i + 512 * wave]);
  };

  stage(0, 0);
  stage(1, 1);

#pragma unroll 1
  for (int ks = 0; ks < nst; ++ks) {
    if (ks + 1 < nst) { WAITV4 } else { WAITV0 }
    BAR;
    if (ks + 2 < nst) stage((ks + 2) % 3, ks + 2);

    const bf16_t* Ab = &As[ks % 3][0];
    const bf16_t* Bb = &Bs[ks % 3][0];
    const int ko = (lane >> 4) * 8;
    bf16x8 af[4], bfr[4];
#pragma unroll
    for (int m = 0; m < 4; ++m)
      af[m] = *(const bf16x8*)&Ab[(row0 + 16 * m + l15) * 32 + ko];
#pragma unroll
    for (int n = 0; n < 4; ++n)
      bfr[n] = *(const bf16x8*)&Bb[(col0 + 16 * n + l15) * 32 + ko];
    WAITL0;
#pragma unroll
    for (int m = 0; m < 4; ++m)
#pragma unroll
      for (int n = 0; n < 4; ++n) acc[m][n] = mfma16(af[m], bfr[n], acc[m][n]);
  }

  const int crow = brow + row0 + (lane >> 4) * 4;
  const int ccol = bcol + col0 + l15;
#pragma unroll
  for (int m = 0; m < 4; ++m)
#pragma unroll
    for (int n = 0; n < 4; ++n)
#pragma unroll
      for (int r = 0; r < 4; ++r) {
        size_t idx = (size_t)(crow + 16 * m + r) * N + (ccol + 16 * n);
        float v = acc[m][n][r] * cscale;
        if (STORE_F32) reinterpret_cast<float*>(Cv)[idx] = v;
        else reinterpret_cast<bf16_t*>(Cv)[idx] = (bf16_t)v;
      }
}

// ---------------- causal flash attention (unchanged from R6) ----------------
#define CROW(r) ((((r) & 3) + 8 * ((r) >> 2)) + 4 * hi)

__global__ __launch_bounds__(256, 1) void attn_fwd(const bf16_t* __restrict__ qkv,
                                                   bf16_t* __restrict__ ctx) {
  __shared__ __align__(128) bf16_t KV[3][2][64 * 64];  // [buf][K|V][4096] = 48 KB
  const int tid = threadIdx.x;
  const int lane = tid & 63;
  const int wv = tid >> 6;
  const int bh = blockIdx.x, p = blockIdx.y;
  const int b = bh >> 4, h = bh & 15;
  const bf16_t* Qg = qkv + (size_t)b * T_ * RS_ + h * DH_;
  const bf16_t* Kg = Qg + 1024;
  const bf16_t* Vg = Qg + 2048;
  bf16_t* Cg = ctx + (size_t)b * T_ * D_ + h * DH_;

  const int hi = lane >> 5;
  const int l31 = lane & 31;
  const int l15 = lane & 15;

  auto stage = [&](int bi, int kt) {
    bf16_t* Kb = &KV[bi][0][0];
    bf16_t* Vb = &KV[bi][1][0];
#pragma unroll
    for (int i = 0; i < 2; ++i) {
      int c2 = i * 256 + tid;
      int r = c2 >> 3, g8 = (c2 & 7) ^ (r & 7);
      gld16(Kg + (size_t)(kt * 64 + r) * RS_ + g8 * 8, Kb + i * 2048 + wv * 512);
    }
#pragma unroll
    for (int i = 0; i < 2; ++i) {
      int c2 = i * 256 + tid;
      int pn = c2 >> 7, k = (c2 >> 1) & 63, half = c2 & 1;
      gld16(Vg + (size_t)(kt * 64 + k) * RS_ + pn * 16 + half * 8, Vb + i * 2048 + wv * 512);
    }
  };

#pragma unroll 1
  for (int phase = 0; phase < 2; ++phase) {
    const int c = phase ? (63 - 4 * p - wv) : (4 * p + wv);
    const int q0 = c * 32;
    const int mynkt = (c >> 1) + 1;
    const int maxnkt = phase ? (32 - 2 * p) : (2 * p + 2);

    BAR;  // previous phase's LDS reads fully retired before re-staging
    stage(0, 0);
    stage(1, 1);

    bf16x8 qf[4];
#pragma unroll
    for (int d = 0; d < 4; ++d)
      qf[d] = *(const bf16x8*)&Qg[(size_t)(q0 + l31) * RS_ + d * 16 + hi * 8];

    f32x16 o[2];
#pragma unroll
    for (int n = 0; n < 2; ++n)
#pragma unroll
      for (int r = 0; r < 16; ++r) o[n][r] = 0.f;
    float mrow = -1e30f, lsum = 0.f;

#pragma unroll 1
    for (int kt = 0; kt < maxnkt; ++kt) {
      if (kt + 1 < maxnkt) { WAITV4 } else { WAITV0 }
      BAR;
      if (kt + 2 < maxnkt) stage((kt + 2) % 3, kt + 2);

      if (kt < mynkt) {
        const bf16_t* Kb = &KV[kt % 3][0][0];
        bf16x8 kf[2][4];
#pragma unroll
        for (int t = 0; t < 2; ++t)
#pragma unroll
          for (int d = 0; d < 4; ++d) {
            int row = 32 * t + l31;
            int col = ((d * 2 + hi) ^ (row & 7)) * 8;
            kf[t][d] = *(const bf16x8*)&Kb[row * 64 + col];
          }
        bf16x8 vf[2][4];
        {
          unsigned vb = lds_addr(&KV[kt % 3][1][0]);
#pragma unroll
          for (int n2 = 0; n2 < 2; ++n2)
#pragma unroll
            for (int ks = 0; ks < 4; ++ks) {
              int pn = 2 * n2 + (l31 >> 4);
              int k0 = ks * 16 + hi * 8;
              unsigned a = vb + pn * 2048 + k0 * 32 + l15 * 8;
              i32x2 lo = tr64(a);
              i32x2 hi4 = tr64o(a);
              union { unsigned u[4]; bf16x8 v; } uu;
              uu.u[0] = (unsigned)lo[0]; uu.u[1] = (unsigned)lo[1];
              uu.u[2] = (unsigned)hi4[0]; uu.u[3] = (unsigned)hi4[1];
              vf[n2][ks] = uu.v;
            }
        }
        WAITL0;

        f32x16 st[2];
#pragma unroll
        for (int t = 0; t < 2; ++t) {
#pragma unroll
          for (int r = 0; r < 16; ++r) st[t][r] = 0.f;
#pragma unroll
          for (int d = 0; d < 4; ++d) st[t] = mfma32(kf[t][d], qf[d], st[t]);
        }
        if (kt == mynkt - 1) {
#pragma unroll
          for (int t = 0; t < 2; ++t)
#pragma unroll
            for (int r = 0; r < 16; ++r)
              if (kt * 64 + 32 * t + CROW(r) > q0 + l31) st[t][r] = -1e30f;
        }
        float pm = -1e30f;
#pragma unroll
        for (int t = 0; t < 2; ++t)
#pragma unroll
          for (int r = 0; r < 16; ++r) pm = fmaxf(pm, st[t][r]);
        pm = fmaxf(pm, __shfl_xor(pm, 32));
        if (!__all(pm - mrow <= 11.0f)) {
          float mn = fmaxf(mrow, pm);
          float scl = exp2f(mrow - mn);
          mrow = mn;
          lsum *= scl;
#pragma unroll
          for (int r = 0; r < 16; ++r) {
            float sr = __shfl(scl, CROW(r));
            o[0][r] *= sr;
            o[1][r] *= sr;
          }
        }
        float ps = 0.f;
#pragma unroll
        for (int t = 0; t < 2; ++t)
#pragma unroll
          for (int r = 0; r < 16; ++r) {
            float e = exp2f(st[t][r] - mrow);
            st[t][r] = e;
            ps += e;
          }
        ps += __shfl_xor(ps, 32);
        lsum += ps;
        unsigned pk[2][8];
#pragma unroll
        for (int t = 0; t < 2; ++t)
#pragma unroll
          for (int j = 0; j < 8; ++j) pk[t][j] = pk2(st[t][2 * j], st[t][2 * j + 1]);
#pragma unroll
        for (int ks = 0; ks < 4; ++ks) {
          const int t = ks >> 1, rb = (ks & 1) * 4;
          unsigned s0 = hi ? pk[t][rb] : pk[t][rb + 2];
          unsigned s1 = hi ? pk[t][rb + 1] : pk[t][rb + 3];
          unsigned r0 = (unsigned)__shfl_xor((int)s0, 32);
          unsigned r1 = (unsigned)__shfl_xor((int)s1, 32);
          union { unsigned u[4]; bf16x8 v; } w;
          if (hi == 0) {
            w.u[0] = pk[t][rb]; w.u[1] = pk[t][rb + 1]; w.u[2] = r0; w.u[3] = r1;
          } else {
            w.u[0] = r0; w.u[1] = r1; w.u[2] = pk[t][rb + 2]; w.u[3] = pk[t][rb + 3];
          }
          o[0] = mfma32(w.v, vf[0][ks], o[0]);
          o[1] = mfma32(w.v, vf[1][ks], o[1]);
        }
      }  // compute guard
    }  // kt

#pragma unroll
    for (int r = 0; r < 16; ++r) {
      float li = __shfl(lsum, CROW(r));
      float inv = 1.0f / li;
      int qrow = q0 + CROW(r);
#pragma unroll
      for (int n2 = 0; n2 < 2; ++n2)
        Cg[(size_t)qrow * D_ + n2 * 32 + l31] = (bf16_t)(o[n2][r] * inv);
    }
  }  // phase
}

// ---------------- launch ----------------
extern "C" void kernel_launch(void* const* d_in, const int* in_sizes, int n_in,
                              void* d_out, int out_size, void* d_ws, size_t ws_size,
                              hipStream_t stream) {
  const float* x   = (const float*)d_in[0];
  const float* w_q = (const float*)d_in[1];
  const float* w_k = (const float*)d_in[2];
  const float* w_v = (const float*)d_in[3];
  const float* w_o = (const float*)d_in[4];

  const int M = B_ * T_;              // 4096
  const size_t XN = (size_t)M * D_;   // 4M
  const size_t WN = (size_t)D_ * D_;  // 1M

  bf16_t* ws = (bf16_t*)d_ws;
  bf16_t* xb   = ws;            // 4M
  bf16_t* wqb  = xb + XN;       // 3M (q,k,v) + 1M (o) contiguous
  bf16_t* wob  = wqb + 3 * WN;
  bf16_t* qkv  = wob + WN;      // [4096][3072] = 12M
  bf16_t* ctx  = qkv + (size_t)M * RS_;  // 4M

  cvt_x<<<(int)(XN / 4 / 256), 256, 0, stream>>>(x, xb, (int)(XN / 4));
  cvt_w4<<<dim3((int)(WN / 4 / 256), 4), 256, 0, stream>>>(w_q, w_k, w_v, w_o, wqb, (int)(WN / 4));

  // fused QKV GEMM: B = [w_q; w_k; w_v] (3072 x 1024), q-part pre-scaled (exp2 domain)
  gemm_nt<false, true><<<dim3(RS_ / 128, M / 128), 256, 0, stream>>>(xb, wqb, qkv, M, RS_, D_);

  attn_fwd<<<dim3(B_ * H_, 8), 256, 0, stream>>>(qkv, ctx);

  gemm_nt<true, false><<<dim3(D_ / 128, M / 128), 256, 0, stream>>>(ctx, wob, d_out, M, D_, D_);
}